// Round 12
// baseline (422.904 us; speedup 1.0000x reference)
//
#include <hip/hip_runtime.h>

#define RNUM 256
#define NB 64
#define KSEL 8
#define SNUM 256
#define HDIM 128
#define FEAT 32
#define EMB 16
#define NAPP 100
#define CINDIM 52
#define STEPF 0.5f
#define VIS_T 0.01f
#define TERM_T 0.99f
#define T_EPS 1e-4f

// packed-weight sizes (ushort units) per block
#define W2P_SZ   16384      // 8 ntiles * 4 ksteps * 64 lanes * 8
#define WFDP_SZ  6144       // 3 ntiles * 4 ksteps * 64 * 8   (N=48: feat32 | Wd | 0)
#define WC1P_SZ  4096       // 4 ntiles * 2 ksteps * 64 * 8   (K=64: 52 | 0-pad)
#define BLK_SZ   (W2P_SZ + WFDP_SZ + WC1P_SZ)   // 26624 ushorts = 53248 B

typedef __attribute__((ext_vector_type(8))) short bh8;
typedef __attribute__((ext_vector_type(4))) float f32x4;

__device__ __forceinline__ unsigned short f2bf(float f) {
    unsigned int u = __float_as_uint(f);
    unsigned int r = (u + 0x7fffu + ((u >> 16) & 1u)) >> 16;
    return (unsigned short)r;
}

// ---------------- pack: weights -> MFMA B-fragment layout (proven R6) ----------------
__global__ __launch_bounds__(256) void pack_kernel(
    const float* __restrict__ W2, const float* __restrict__ Wf,
    const float* __restrict__ Wd, const float* __restrict__ Wc1,
    unsigned short* __restrict__ wsu)
{
    const int blk = blockIdx.x, t = threadIdx.x;
    unsigned short* w2p  = wsu + (size_t)blk * BLK_SZ;
    unsigned short* wfdp = w2p + W2P_SZ;
    unsigned short* wc1p = w2p + W2P_SZ + WFDP_SZ;
    const float* W2b  = W2  + (size_t)blk * HDIM * HDIM;
    const float* Wfb  = Wf  + (size_t)blk * HDIM * FEAT;
    const float* Wdb  = Wd  + (size_t)blk * HDIM;
    const float* Wc1b = Wc1 + (size_t)blk * CINDIM * 64;

    for (int slot = t; slot < 8*4*64; slot += 256) {
        int unit = slot >> 6, l = slot & 63;
        int n0 = unit >> 2, k0 = unit & 3, q = l >> 4, lr = l & 15;
        bh8 v;
        #pragma unroll
        for (int bb = 0; bb < 8; bb++) {
            int row = k0*32 + 8*q + bb;
            v[bb] = (short)f2bf(W2b[row*HDIM + n0*16 + lr]);
        }
        ((bh8*)w2p)[slot] = v;
    }
    for (int slot = t; slot < 3*4*64; slot += 256) {
        int unit = slot >> 6, l = slot & 63;
        int n0 = unit >> 2, k0 = unit & 3, q = l >> 4, lr = l & 15;
        int gcol = n0*16 + lr;
        bh8 v;
        #pragma unroll
        for (int bb = 0; bb < 8; bb++) {
            int row = k0*32 + 8*q + bb;
            float val = (gcol < FEAT) ? Wfb[row*FEAT + gcol]
                       : ((gcol == FEAT) ? Wdb[row] : 0.f);
            v[bb] = (short)f2bf(val);
        }
        ((bh8*)wfdp)[slot] = v;
    }
    for (int slot = t; slot < 4*2*64; slot += 256) {
        int unit = slot >> 6, l = slot & 63;
        int n0 = unit >> 1, k0 = unit & 1, q = l >> 4, lr = l & 15;
        bh8 v;
        #pragma unroll
        for (int bb = 0; bb < 8; bb++) {
            int row = k0*32 + 8*q + bb;
            float val = (row < CINDIM) ? Wc1b[row*64 + n0*16 + lr] : 0.f;
            v[bb] = (short)f2bf(val);
        }
        ((bh8*)wc1p)[slot] = v;
    }
}

// ---------------- sel: per-ray top-8 block selection (proven R6 logic) ----------------
__global__ __launch_bounds__(64) void sel_kernel(
    const float* __restrict__ ro, const float* __restrict__ rd,
    const float* __restrict__ bc, const float* __restrict__ br,
    int* __restrict__ selw, float* __restrict__ cselw)
{
    const int r = blockIdx.x, t = threadIdx.x;
    __shared__ float distL[NB];
    __shared__ int selLds[KSEL];
    const float ox = ro[r*3], oy = ro[r*3+1], oz = ro[r*3+2];
    const float dx = rd[r*3], dy = rd[r*3+1], dz = rd[r*3+2];
    {
        const int nb = t;
        float a = dx*dx + dy*dy + dz*dz;
        float cx = bc[nb*3], cy = bc[nb*3+1], cz = bc[nb*3+2];
        float rad = br[nb];
        float ocx = ox-cx, ocy = oy-cy, ocz = oz-cz;
        float bq = 2.f*(ocx*dx + ocy*dy + ocz*dz);
        float cq = ocx*ocx + ocy*ocy + ocz*ocz - rad*rad;
        float disc = bq*bq - 4.f*a*cq;
        float sq = disc > 0.f ? sqrtf(disc) : (disc >= 0.f ? 1.f : 0.f);
        float t1 = (-bq - sq) / (2.f*a);
        float t2 = (-bq + sq) / (2.f*a);
        float th = t1 > 0.f ? t1 : t2;
        bool valid = (disc >= 0.f) && (th > 0.f);
        float hx = ox + th*dx - cx, hy = oy + th*dy - cy, hz = oz + th*dz - cz;
        distL[nb] = valid ? sqrtf(hx*hx + hy*hy + hz*hz) : INFINITY;
    }
    __syncthreads();
    if (t == 0) {
        for (int kk = 0; kk < KSEL; kk++) {
            float bd2 = INFINITY; int bi = -1;
            for (int j = 0; j < NB; j++) { if (distL[j] < bd2) { bd2 = distL[j]; bi = j; } }
            selLds[kk] = bi;
            if (bi >= 0) distL[bi] = INFINITY;
        }
    }
    __syncthreads();
    if (t < KSEL) selw[r*KSEL + t] = selLds[t];
    if (t < KSEL*3) {
        int kk = t/3, j = t%3;
        int b = selLds[kk];
        cselw[r*KSEL*3 + t] = (b >= 0) ? bc[b*3+j] : 0.f;
    }
}

// ---------------- mlp: one WG per (ray, k-slot); 4 waves x 64 samples ----------------
// R12: EXACT R9 body (no launch_bounds -> 256-reg tier, proven no-spill, 215us)
// with all intra-loop __syncthreads REMOVED. The per-wave slab (SLAB+wave*4096)
// is wave-private; wvL reads are wave-range-local; so waves need no rendezvous.
// Intra-wave LDS write->read ordering is handled by compiler lgkmcnt waits
// (same-array dependence). Barriers were gating all 4 waves on the slowest
// wave's L2 stall ~10x/pass.
__global__ void mlp_kernel(
    const float* __restrict__ ro, const float* __restrict__ rd,
    const float* __restrict__ nearp, const float* __restrict__ expo,
    const int* __restrict__ aid,
    const float* __restrict__ W1, const float* __restrict__ b1,
    const float* __restrict__ b2, const float* __restrict__ bd,
    const float* __restrict__ bc1, const float* __restrict__ Wc2,
    const float* __restrict__ bc2, const float* __restrict__ app_emb,
    const unsigned short* __restrict__ wsu,
    const int* __restrict__ selw, const float* __restrict__ cselw,
    float* __restrict__ tdp, float* __restrict__ c0p,
    float* __restrict__ c1p, float* __restrict__ c2p)
{
    const int g = blockIdx.x, r = g >> 3, kk = g & 7, t = threadIdx.x;
    const int wave = t >> 6, l = t & 63, lq = l >> 4, lr = l & 15;

    __shared__ int   selLds[KSEL];
    __shared__ float cselLds[KSEL*3];
    __shared__ float wvL[SNUM];
    __shared__ __align__(16) float w1p[HDIM*4];     // (w1x,w1y,w1z,b1)
    __shared__ float b2L[HDIM], bc1L[64], wc2L[192], bc2L[3], embL[EMB];
    __shared__ float bdL;
    // per-wave 4096-ushort slab: H2 tile [32][128]; CIN tile [32][64] aliases it
    __shared__ __align__(16) unsigned short SLAB[4*4096];   // 32 KB

    float* tdg = tdp + (size_t)g * SNUM;
    float* c0g = c0p + (size_t)g * SNUM;
    float* c1g = c1p + (size_t)g * SNUM;
    float* c2g = c2p + (size_t)g * SNUM;

    if (t < KSEL) selLds[t] = selw[r*KSEL + t];
    if (t < KSEL*3) cselLds[t] = cselw[r*KSEL*3 + t];
    __syncthreads();
    const int b = selLds[kk];
    if (b < 0) {     // uniform: zero partials, exit
        tdg[t] = 0.f; c0g[t] = 0.f; c1g[t] = 0.f; c2g[t] = 0.f;
        return;
    }

    const float ox = ro[r*3], oy = ro[r*3+1], oz = ro[r*3+2];
    const float dx = rd[r*3], dy = rd[r*3+1], dz = rd[r*3+2];
    const float nearr = nearp[r];
    const float expv  = expo[r];
    const int   aidr  = aid[r];

    // per-sample wv for this kk (same formula as proven wv_at)
    {
        const int s = t;
        float ts = nearr + STEPF*(float)s;
        float px = ox + ts*dx, py = oy + ts*dy, pz = oz + ts*dz;
        float wsum = 0.f, invk = 0.f;
        #pragma unroll
        for (int k2 = 0; k2 < KSEL; k2++) {
            if (selLds[k2] >= 0) {
                float ex = px - cselLds[k2*3], ey = py - cselLds[k2*3+1], ez = pz - cselLds[k2*3+2];
                float inv = 1.f / (sqrtf(ex*ex + ey*ey + ez*ez) + 1e-6f);
                wsum += inv;
                if (k2 == kk) invk = inv;
            }
        }
        float w = (wsum > 0.f) ? invk / fmaxf(wsum, 1e-12f) : 0.f;
        wvL[s] = (w >= VIS_T) ? w : 0.f;
    }
    // small vectors
    if (t < HDIM) {
        const float* w1g = W1 + (size_t)b*3*HDIM;
        w1p[t*4+0] = w1g[t];
        w1p[t*4+1] = w1g[HDIM+t];
        w1p[t*4+2] = w1g[2*HDIM+t];
        w1p[t*4+3] = b1[b*HDIM+t];
        b2L[t] = b2[b*HDIM+t];
    } else {
        int idx = t - 128;
        if (idx < 64) bc1L[idx] = bc1[b*64 + idx];
        else {
            int i2 = idx - 64;
            wc2L[i2]       = Wc2[b*192 + i2];
            wc2L[i2+64]    = Wc2[b*192 + i2+64];
            wc2L[i2+128]   = Wc2[b*192 + i2+128];
        }
    }
    if (t < EMB) embL[t] = app_emb[((size_t)b*NAPP + aidr)*EMB + t];
    if (t == 16) bdL = bd[b];
    if (t >= 20 && t < 23) bc2L[t-20] = bc2[b*3 + (t-20)];
    __syncthreads();     // the ONLY barrier: staging -> compute

    const unsigned short* w2p  = wsu + (size_t)b*BLK_SZ;
    const unsigned short* wfdp = w2p + W2P_SZ;
    const unsigned short* wc1p = wfdp + WFDP_SZ;
    unsigned short* slab = SLAB + wave*4096;
    const f32x4 zero4 = {0.f, 0.f, 0.f, 0.f};

    for (int p = 0; p < 2; p++) {
        const int sbase = wave*64 + p*32;

        // ---- A-frags of H1 in registers (rows = samples sbase + mt*16 + lr) ----
        float pxm[2], pym[2], pzm[2];
        #pragma unroll
        for (int mt = 0; mt < 2; mt++) {
            int s = sbase + mt*16 + lr;
            float ts = nearr + STEPF*(float)s;
            pxm[mt] = ox + ts*dx; pym[mt] = oy + ts*dy; pzm[mt] = oz + ts*dz;
        }
        bh8 afrag[2][4];
        #pragma unroll
        for (int mt = 0; mt < 2; mt++)
        #pragma unroll
        for (int k0 = 0; k0 < 4; k0++)
        #pragma unroll
        for (int bb = 0; bb < 8; bb++) {
            int i = k0*32 + 8*lq + bb;
            float4 w = ((const float4*)w1p)[i];
            float v = fmaf(pxm[mt], w.x, fmaf(pym[mt], w.y, fmaf(pzm[mt], w.z, w.w)));
            afrag[mt][k0][bb] = (short)f2bf(fmaxf(v, 0.f));
        }

        // ---- GEMM1: H2[32][128] = relu(H1 . W2 + b2), in TWO nt-halves ----
        #pragma unroll
        for (int h = 0; h < 2; h++) {
            f32x4 acc1[2][4];
            #pragma unroll
            for (int mt = 0; mt < 2; mt++)
            #pragma unroll
            for (int n4 = 0; n4 < 4; n4++) acc1[mt][n4] = zero4;
            #pragma unroll
            for (int n4 = 0; n4 < 4; n4++) {
                int nt = h*4 + n4;
                bh8 bf0 = ((const bh8*)w2p)[(nt*4+0)*64 + l];
                bh8 bf1 = ((const bh8*)w2p)[(nt*4+1)*64 + l];
                bh8 bf2 = ((const bh8*)w2p)[(nt*4+2)*64 + l];
                bh8 bf3 = ((const bh8*)w2p)[(nt*4+3)*64 + l];
                #pragma unroll
                for (int mt = 0; mt < 2; mt++) {
                    acc1[mt][n4] = __builtin_amdgcn_mfma_f32_16x16x32_bf16(afrag[mt][0], bf0, acc1[mt][n4], 0,0,0);
                    acc1[mt][n4] = __builtin_amdgcn_mfma_f32_16x16x32_bf16(afrag[mt][1], bf1, acc1[mt][n4], 0,0,0);
                    acc1[mt][n4] = __builtin_amdgcn_mfma_f32_16x16x32_bf16(afrag[mt][2], bf2, acc1[mt][n4], 0,0,0);
                    acc1[mt][n4] = __builtin_amdgcn_mfma_f32_16x16x32_bf16(afrag[mt][3], bf3, acc1[mt][n4], 0,0,0);
                }
            }
            // epilogue for this half -> H2 slab (swizzled)
            #pragma unroll
            for (int mt = 0; mt < 2; mt++)
            #pragma unroll
            for (int n4 = 0; n4 < 4; n4++) {
                int col = (h*4 + n4)*16 + lr;
                float bb2 = b2L[col];
                #pragma unroll
                for (int reg = 0; reg < 4; reg++) {
                    int sl = mt*16 + lq*4 + reg;
                    float v = fmaxf(acc1[mt][n4][reg] + bb2, 0.f);
                    int g2 = (col >> 3) ^ (sl & 7);
                    slab[sl*128 + (g2<<3) + (col & 7)] = f2bf(v);
                }
            }
            __builtin_amdgcn_sched_barrier(0);   // keep halves' register pressure separate
        }

        // ---- extract A-frags of H2 into registers (wave-private slab; compiler
        //      inserts lgkmcnt for the same-array write->read dependence) ----
        bh8 afr2[2][4];
        #pragma unroll
        for (int mt = 0; mt < 2; mt++)
        #pragma unroll
        for (int k0 = 0; k0 < 4; k0++) {
            int sl = mt*16 + lr;
            int g2 = (k0*4 + lq) ^ (sl & 7);
            afr2[mt][k0] = *(const bh8*)&slab[sl*128 + (g2<<3)];
        }

        // ---- GEMM2: [feat(32) | sigma | pad] = H2 . [Wf|Wd|0] ----
        f32x4 acc2[2][3];
        #pragma unroll
        for (int mt = 0; mt < 2; mt++)
        #pragma unroll
        for (int nt = 0; nt < 3; nt++) acc2[mt][nt] = zero4;
        #pragma unroll
        for (int nt = 0; nt < 3; nt++) {
            bh8 bf0 = ((const bh8*)wfdp)[(nt*4+0)*64 + l];
            bh8 bf1 = ((const bh8*)wfdp)[(nt*4+1)*64 + l];
            bh8 bf2 = ((const bh8*)wfdp)[(nt*4+2)*64 + l];
            bh8 bf3 = ((const bh8*)wfdp)[(nt*4+3)*64 + l];
            #pragma unroll
            for (int mt = 0; mt < 2; mt++) {
                acc2[mt][nt] = __builtin_amdgcn_mfma_f32_16x16x32_bf16(afr2[mt][0], bf0, acc2[mt][nt], 0,0,0);
                acc2[mt][nt] = __builtin_amdgcn_mfma_f32_16x16x32_bf16(afr2[mt][1], bf1, acc2[mt][nt], 0,0,0);
                acc2[mt][nt] = __builtin_amdgcn_mfma_f32_16x16x32_bf16(afr2[mt][2], bf2, acc2[mt][nt], 0,0,0);
                acc2[mt][nt] = __builtin_amdgcn_mfma_f32_16x16x32_bf16(afr2[mt][3], bf3, acc2[mt][nt], 0,0,0);
            }
        }
        // sigma (col 32 = ntile2,col0): softplus * wv -> partial store
        if (lr == 0) {
            #pragma unroll
            for (int mt = 0; mt < 2; mt++)
            #pragma unroll
            for (int reg = 0; reg < 4; reg++) {
                int sg = sbase + mt*16 + lq*4 + reg;
                float x = acc2[mt][2][reg] + bdL;
                float sgm = log1pf(expf(-fabsf(x))) + fmaxf(x, 0.f);
                tdg[sg] = sgm * wvL[sg];
            }
        }
        // feat -> CIN slab cols 0..31 (WAR on slab: compiler orders via lgkmcnt)
        #pragma unroll
        for (int mt = 0; mt < 2; mt++)
        #pragma unroll
        for (int nt = 0; nt < 2; nt++) {
            int f = nt*16 + lr;
            #pragma unroll
            for (int reg = 0; reg < 4; reg++) {
                int sl = mt*16 + lq*4 + reg;
                int g2 = (f >> 3) ^ (sl & 7);
                slab[sl*64 + (g2<<3) + (f & 7)] = f2bf(acc2[mt][nt][reg]);
            }
        }
        // CIN extras cols 32..63 = [d(3), emb(16), exp(1), 0-pad]
        {
            int sl = l & 31, cg = l >> 5;
            #pragma unroll
            for (int j = 0; j < 16; j++) {
                int c = 32 + cg*16 + j;
                float v;
                if (c < 35)       v = (c==32 ? dx : (c==33 ? dy : dz));
                else if (c < 51)  v = embL[c-35];
                else if (c == 51) v = expv;
                else              v = 0.f;
                int g2 = (c >> 3) ^ (sl & 7);
                slab[sl*64 + (g2<<3) + (c & 7)] = f2bf(v);
            }
        }

        // ---- GEMM3: HC[32][64] = relu(CIN . Wc1 + bc1) ----
        bh8 afr3[2][2];
        #pragma unroll
        for (int mt = 0; mt < 2; mt++)
        #pragma unroll
        for (int k0 = 0; k0 < 2; k0++) {
            int sl = mt*16 + lr;
            int g2 = (k0*4 + lq) ^ (sl & 7);
            afr3[mt][k0] = *(const bh8*)&slab[sl*64 + (g2<<3)];
        }
        f32x4 acc3[2][4];
        #pragma unroll
        for (int mt = 0; mt < 2; mt++)
        #pragma unroll
        for (int nt = 0; nt < 4; nt++) acc3[mt][nt] = zero4;
        #pragma unroll
        for (int nt = 0; nt < 4; nt++) {
            bh8 bf0 = ((const bh8*)wc1p)[(nt*2+0)*64 + l];
            bh8 bf1 = ((const bh8*)wc1p)[(nt*2+1)*64 + l];
            #pragma unroll
            for (int mt = 0; mt < 2; mt++) {
                acc3[mt][nt] = __builtin_amdgcn_mfma_f32_16x16x32_bf16(afr3[mt][0], bf0, acc3[mt][nt], 0,0,0);
                acc3[mt][nt] = __builtin_amdgcn_mfma_f32_16x16x32_bf16(afr3[mt][1], bf1, acc3[mt][nt], 0,0,0);
            }
        }
        // color: hc=relu(+bc1); dot wc2; 16-lane reduce; sigmoid * wv -> partial store
        #pragma unroll
        for (int mt = 0; mt < 2; mt++)
        #pragma unroll
        for (int reg = 0; reg < 4; reg++) {
            float p0 = 0.f, p1 = 0.f, p2 = 0.f;
            #pragma unroll
            for (int nt = 0; nt < 4; nt++) {
                int e = nt*16 + lr;
                float hc = fmaxf(acc3[mt][nt][reg] + bc1L[e], 0.f);
                p0 = fmaf(hc, wc2L[e*3+0], p0);
                p1 = fmaf(hc, wc2L[e*3+1], p1);
                p2 = fmaf(hc, wc2L[e*3+2], p2);
            }
            #pragma unroll
            for (int m = 1; m < 16; m <<= 1) {
                p0 += __shfl_xor(p0, m);
                p1 += __shfl_xor(p1, m);
                p2 += __shfl_xor(p2, m);
            }
            if (lr == 0) {
                int sg = sbase + mt*16 + lq*4 + reg;
                float wvv = wvL[sg];
                c0g[sg] = wvv / (1.f + expf(-(p0 + bc2L[0])));
                c1g[sg] = wvv / (1.f + expf(-(p1 + bc2L[1])));
                c2g[sg] = wvv / (1.f + expf(-(p2 + bc2L[2])));
            }
        }
        // next pass overwrites slab: intra-wave WAR, compiler-ordered
    }
}

// ---------------- composite: sum k-partials, sequential scan ----------------
__global__ __launch_bounds__(256) void comp_kernel(
    const float* __restrict__ ro, const float* __restrict__ rd,
    const float* __restrict__ nearp, const float* __restrict__ farp,
    const int* __restrict__ selw, const float* __restrict__ cselw,
    const float* __restrict__ tdp, const float* __restrict__ c0p,
    const float* __restrict__ c1p, const float* __restrict__ c2p,
    float* __restrict__ out)
{
    const int r = blockIdx.x, t = threadIdx.x;
    __shared__ int selLds[KSEL];
    __shared__ float cselLds[KSEL*3];
    __shared__ float aLds[SNUM], cn0[SNUM], cn1[SNUM], cn2[SNUM];
    if (t < KSEL) selLds[t] = selw[r*KSEL + t];
    if (t < KSEL*3) cselLds[t] = cselw[r*KSEL*3 + t];
    __syncthreads();
    const float ox = ro[r*3], oy = ro[r*3+1], oz = ro[r*3+2];
    const float dx = rd[r*3], dy = rd[r*3+1], dz = rd[r*3+2];
    const float nearr = nearp[r];
    {
        const int s = t;
        float ts = nearr + STEPF*(float)s;
        float px = ox + ts*dx, py = oy + ts*dy, pz = oz + ts*dz;
        float invv[KSEL]; float wsum = 0.f;
        #pragma unroll
        for (int k2 = 0; k2 < KSEL; k2++) {
            float inv = 0.f;
            if (selLds[k2] >= 0) {
                float ex = px - cselLds[k2*3], ey = py - cselLds[k2*3+1], ez = pz - cselLds[k2*3+2];
                inv = 1.f / (sqrtf(ex*ex + ey*ey + ez*ez) + 1e-6f);
            }
            invv[k2] = inv; wsum += inv;
        }
        float tw = 0.f;
        #pragma unroll
        for (int k2 = 0; k2 < KSEL; k2++) {
            float w = (wsum > 0.f) ? invv[k2] / fmaxf(wsum, 1e-12f) : 0.f;
            if (w >= VIS_T && selLds[k2] >= 0) tw += w;
        }
        float td = 0.f, c0 = 0.f, c1 = 0.f, c2 = 0.f;
        #pragma unroll
        for (int k2 = 0; k2 < KSEL; k2++) {
            size_t gg = (size_t)(r*KSEL + k2)*SNUM + s;
            td += tdp[gg]; c0 += c0p[gg]; c1 += c1p[gg]; c2 += c2p[gg];
        }
        float a = fminf(fmaxf(1.f - expf(-td*STEPF), 0.f), 1.f);
        if (tw > 0.f) {
            float dv = fmaxf(tw, 1e-12f);
            c0 /= dv; c1 /= dv; c2 /= dv;
        }
        aLds[s] = a; cn0[s] = c0; cn1[s] = c1; cn2[s] = c2;
    }
    __syncthreads();
    if (t == 0) {
        const float farr = farp[r];
        float T = 1.f, acc = 0.f, rgb0=0.f, rgb1=0.f, rgb2=0.f, dep=0.f;
        for (int s = 0; s < SNUM; s++) {
            float ts = nearr + STEPF*(float)s;
            bool alive = (ts < farr) && (T > T_EPS) && (acc <= TERM_T);
            float a = aLds[s];
            float wgt = alive ? T*a : 0.f;
            rgb0 += wgt*cn0[s]; rgb1 += wgt*cn1[s]; rgb2 += wgt*cn2[s];
            acc += wgt;
            dep += wgt*ts;
            T *= alive ? (1.f - a) : 1.f;
        }
        float depth = dep / fmaxf(acc, 1e-6f);
        out[r*3+0] = rgb0;
        out[r*3+1] = rgb1;
        out[r*3+2] = rgb2;
        out[RNUM*3 + r]        = depth;
        out[RNUM*3 + RNUM + r] = acc;
    }
}

extern "C" void kernel_launch(void* const* d_in, const int* in_sizes, int n_in,
                              void* d_out, int out_size, void* d_ws, size_t ws_size,
                              hipStream_t stream) {
    const float* ro    = (const float*)d_in[0];
    const float* rd    = (const float*)d_in[1];
    const float* bc    = (const float*)d_in[2];
    const float* br    = (const float*)d_in[3];
    const int*   aidp  = (const int*)d_in[4];
    const float* expo  = (const float*)d_in[5];
    const float* nearp = (const float*)d_in[6];
    const float* farp  = (const float*)d_in[7];
    const float* W1    = (const float*)d_in[8];
    const float* b1    = (const float*)d_in[9];
    const float* W2    = (const float*)d_in[10];
    const float* b2    = (const float*)d_in[11];
    const float* Wd    = (const float*)d_in[12];
    const float* bd    = (const float*)d_in[13];
    const float* Wf    = (const float*)d_in[14];
    const float* Wc1   = (const float*)d_in[15];
    const float* bc1   = (const float*)d_in[16];
    const float* Wc2   = (const float*)d_in[17];
    const float* bc2   = (const float*)d_in[18];
    const float* appe  = (const float*)d_in[19];
    float* outp = (float*)d_out;

    // workspace layout (float units from base)
    float* wsf = (float*)d_ws;
    unsigned short* wsu = (unsigned short*)d_ws;          // 64*26624 ush = 3,407,872 B
    int*   selw  = (int*)  (wsf + 851968);                // 2048 ints
    float* cselw =         wsf + 854016;                  // 6144 f32
    float* tdp   =         wsf + 860160;                  // 2048*256
    float* c0p   =         tdp + 2048*SNUM;
    float* c1p   =         c0p + 2048*SNUM;
    float* c2p   =         c1p + 2048*SNUM;               // end ~11.83 MB

    pack_kernel<<<NB, 256, 0, stream>>>(W2, Wf, Wd, Wc1, wsu);
    sel_kernel<<<RNUM, 64, 0, stream>>>(ro, rd, bc, br, selw, cselw);
    mlp_kernel<<<RNUM*KSEL, 256, 0, stream>>>(ro, rd, nearp, expo, aidp,
                                              W1, b1, b2, bd, bc1, Wc2, bc2, appe,
                                              wsu, selw, cselw, tdp, c0p, c1p, c2p);
    comp_kernel<<<RNUM, 256, 0, stream>>>(ro, rd, nearp, farp, selw, cselw,
                                          tdp, c0p, c1p, c2p, outp);
}

// Round 13
// 328.023 us; speedup vs baseline: 1.2893x; 1.2893x over previous
//
#include <hip/hip_runtime.h>

#define RNUM 256
#define NB 64
#define KSEL 8
#define SNUM 256
#define HDIM 128
#define FEAT 32
#define EMB 16
#define NAPP 100
#define CINDIM 52
#define STEPF 0.5f
#define VIS_T 0.01f
#define TERM_T 0.99f
#define T_EPS 1e-4f

// packed-weight sizes (ushort units) per block
#define W2P_SZ   16384      // 8 ntiles * 4 ksteps * 64 lanes * 8
#define WFDP_SZ  6144       // 3 ntiles * 4 ksteps * 64 * 8   (N=48: feat32 | Wd | 0)
#define WC1P_SZ  4096       // 4 ntiles * 2 ksteps * 64 * 8   (K=64: 52 | 0-pad)
#define BLK_SZ   (W2P_SZ + WFDP_SZ + WC1P_SZ)   // 26624 ushorts = 53248 B

typedef __attribute__((ext_vector_type(8))) short bh8;
typedef __attribute__((ext_vector_type(4))) float f32x4;

// Intra-wave phase fence: orders LDS ops (lgkmcnt) and pins the instruction
// scheduler (sched_barrier) exactly like __syncthreads did for regalloc,
// WITHOUT the cross-wave rendezvous. Legal because the slab + wvL + partial
// ranges touched inside the pass loop are wave-private.
#define WAVE_FENCE() do { \
    asm volatile("s_waitcnt lgkmcnt(0)" ::: "memory"); \
    __builtin_amdgcn_sched_barrier(0); \
} while (0)

__device__ __forceinline__ unsigned short f2bf(float f) {
    unsigned int u = __float_as_uint(f);
    unsigned int r = (u + 0x7fffu + ((u >> 16) & 1u)) >> 16;
    return (unsigned short)r;
}

// ---------------- pack: weights -> MFMA B-fragment layout (proven R6) ----------------
__global__ __launch_bounds__(256) void pack_kernel(
    const float* __restrict__ W2, const float* __restrict__ Wf,
    const float* __restrict__ Wd, const float* __restrict__ Wc1,
    unsigned short* __restrict__ wsu)
{
    const int blk = blockIdx.x, t = threadIdx.x;
    unsigned short* w2p  = wsu + (size_t)blk * BLK_SZ;
    unsigned short* wfdp = w2p + W2P_SZ;
    unsigned short* wc1p = w2p + W2P_SZ + WFDP_SZ;
    const float* W2b  = W2  + (size_t)blk * HDIM * HDIM;
    const float* Wfb  = Wf  + (size_t)blk * HDIM * FEAT;
    const float* Wdb  = Wd  + (size_t)blk * HDIM;
    const float* Wc1b = Wc1 + (size_t)blk * CINDIM * 64;

    for (int slot = t; slot < 8*4*64; slot += 256) {
        int unit = slot >> 6, l = slot & 63;
        int n0 = unit >> 2, k0 = unit & 3, q = l >> 4, lr = l & 15;
        bh8 v;
        #pragma unroll
        for (int bb = 0; bb < 8; bb++) {
            int row = k0*32 + 8*q + bb;
            v[bb] = (short)f2bf(W2b[row*HDIM + n0*16 + lr]);
        }
        ((bh8*)w2p)[slot] = v;
    }
    for (int slot = t; slot < 3*4*64; slot += 256) {
        int unit = slot >> 6, l = slot & 63;
        int n0 = unit >> 2, k0 = unit & 3, q = l >> 4, lr = l & 15;
        int gcol = n0*16 + lr;
        bh8 v;
        #pragma unroll
        for (int bb = 0; bb < 8; bb++) {
            int row = k0*32 + 8*q + bb;
            float val = (gcol < FEAT) ? Wfb[row*FEAT + gcol]
                       : ((gcol == FEAT) ? Wdb[row] : 0.f);
            v[bb] = (short)f2bf(val);
        }
        ((bh8*)wfdp)[slot] = v;
    }
    for (int slot = t; slot < 4*2*64; slot += 256) {
        int unit = slot >> 6, l = slot & 63;
        int n0 = unit >> 1, k0 = unit & 1, q = l >> 4, lr = l & 15;
        bh8 v;
        #pragma unroll
        for (int bb = 0; bb < 8; bb++) {
            int row = k0*32 + 8*q + bb;
            float val = (row < CINDIM) ? Wc1b[row*64 + n0*16 + lr] : 0.f;
            v[bb] = (short)f2bf(val);
        }
        ((bh8*)wc1p)[slot] = v;
    }
}

// ---------------- sel: per-ray top-8 block selection (proven R6 logic) ----------------
__global__ __launch_bounds__(64) void sel_kernel(
    const float* __restrict__ ro, const float* __restrict__ rd,
    const float* __restrict__ bc, const float* __restrict__ br,
    int* __restrict__ selw, float* __restrict__ cselw)
{
    const int r = blockIdx.x, t = threadIdx.x;
    __shared__ float distL[NB];
    __shared__ int selLds[KSEL];
    const float ox = ro[r*3], oy = ro[r*3+1], oz = ro[r*3+2];
    const float dx = rd[r*3], dy = rd[r*3+1], dz = rd[r*3+2];
    {
        const int nb = t;
        float a = dx*dx + dy*dy + dz*dz;
        float cx = bc[nb*3], cy = bc[nb*3+1], cz = bc[nb*3+2];
        float rad = br[nb];
        float ocx = ox-cx, ocy = oy-cy, ocz = oz-cz;
        float bq = 2.f*(ocx*dx + ocy*dy + ocz*dz);
        float cq = ocx*ocx + ocy*ocy + ocz*ocz - rad*rad;
        float disc = bq*bq - 4.f*a*cq;
        float sq = disc > 0.f ? sqrtf(disc) : (disc >= 0.f ? 1.f : 0.f);
        float t1 = (-bq - sq) / (2.f*a);
        float t2 = (-bq + sq) / (2.f*a);
        float th = t1 > 0.f ? t1 : t2;
        bool valid = (disc >= 0.f) && (th > 0.f);
        float hx = ox + th*dx - cx, hy = oy + th*dy - cy, hz = oz + th*dz - cz;
        distL[nb] = valid ? sqrtf(hx*hx + hy*hy + hz*hz) : INFINITY;
    }
    __syncthreads();
    if (t == 0) {
        for (int kk = 0; kk < KSEL; kk++) {
            float bd2 = INFINITY; int bi = -1;
            for (int j = 0; j < NB; j++) { if (distL[j] < bd2) { bd2 = distL[j]; bi = j; } }
            selLds[kk] = bi;
            if (bi >= 0) distL[bi] = INFINITY;
        }
    }
    __syncthreads();
    if (t < KSEL) selw[r*KSEL + t] = selLds[t];
    if (t < KSEL*3) {
        int kk = t/3, j = t%3;
        int b = selLds[kk];
        cselw[r*KSEL*3 + t] = (b >= 0) ? bc[b*3+j] : 0.f;
    }
}

// ---------------- mlp: one WG per (ray, k-slot); 4 waves x 64 samples ----------------
// R13: EXACT R9 body (no launch_bounds = 256-reg tier, proven no-spill, 215us),
// with intra-loop __syncthreads replaced by WAVE_FENCE (lgkmcnt drain +
// sched_barrier). R12 proved barriers were doubling as regalloc fences:
// removing them outright caused a pressure blowup (VGPR 64, 398 MB spill).
// WAVE_FENCE keeps the scheduling fence, drops the cross-wave stall coupling.
__global__ void mlp_kernel(
    const float* __restrict__ ro, const float* __restrict__ rd,
    const float* __restrict__ nearp, const float* __restrict__ expo,
    const int* __restrict__ aid,
    const float* __restrict__ W1, const float* __restrict__ b1,
    const float* __restrict__ b2, const float* __restrict__ bd,
    const float* __restrict__ bc1, const float* __restrict__ Wc2,
    const float* __restrict__ bc2, const float* __restrict__ app_emb,
    const unsigned short* __restrict__ wsu,
    const int* __restrict__ selw, const float* __restrict__ cselw,
    float* __restrict__ tdp, float* __restrict__ c0p,
    float* __restrict__ c1p, float* __restrict__ c2p)
{
    const int g = blockIdx.x, r = g >> 3, kk = g & 7, t = threadIdx.x;
    const int wave = t >> 6, l = t & 63, lq = l >> 4, lr = l & 15;

    __shared__ int   selLds[KSEL];
    __shared__ float cselLds[KSEL*3];
    __shared__ float wvL[SNUM];
    __shared__ __align__(16) float w1p[HDIM*4];     // (w1x,w1y,w1z,b1)
    __shared__ float b2L[HDIM], bc1L[64], wc2L[192], bc2L[3], embL[EMB];
    __shared__ float bdL;
    // per-wave 4096-ushort slab: H2 tile [32][128]; CIN tile [32][64] aliases it
    __shared__ __align__(16) unsigned short SLAB[4*4096];   // 32 KB

    float* tdg = tdp + (size_t)g * SNUM;
    float* c0g = c0p + (size_t)g * SNUM;
    float* c1g = c1p + (size_t)g * SNUM;
    float* c2g = c2p + (size_t)g * SNUM;

    if (t < KSEL) selLds[t] = selw[r*KSEL + t];
    if (t < KSEL*3) cselLds[t] = cselw[r*KSEL*3 + t];
    __syncthreads();
    const int b = selLds[kk];
    if (b < 0) {     // uniform: zero partials, exit
        tdg[t] = 0.f; c0g[t] = 0.f; c1g[t] = 0.f; c2g[t] = 0.f;
        return;
    }

    const float ox = ro[r*3], oy = ro[r*3+1], oz = ro[r*3+2];
    const float dx = rd[r*3], dy = rd[r*3+1], dz = rd[r*3+2];
    const float nearr = nearp[r];
    const float expv  = expo[r];
    const int   aidr  = aid[r];

    // per-sample wv for this kk (same formula as proven wv_at)
    {
        const int s = t;
        float ts = nearr + STEPF*(float)s;
        float px = ox + ts*dx, py = oy + ts*dy, pz = oz + ts*dz;
        float wsum = 0.f, invk = 0.f;
        #pragma unroll
        for (int k2 = 0; k2 < KSEL; k2++) {
            if (selLds[k2] >= 0) {
                float ex = px - cselLds[k2*3], ey = py - cselLds[k2*3+1], ez = pz - cselLds[k2*3+2];
                float inv = 1.f / (sqrtf(ex*ex + ey*ey + ez*ez) + 1e-6f);
                wsum += inv;
                if (k2 == kk) invk = inv;
            }
        }
        float w = (wsum > 0.f) ? invk / fmaxf(wsum, 1e-12f) : 0.f;
        wvL[s] = (w >= VIS_T) ? w : 0.f;
    }
    // small vectors
    if (t < HDIM) {
        const float* w1g = W1 + (size_t)b*3*HDIM;
        w1p[t*4+0] = w1g[t];
        w1p[t*4+1] = w1g[HDIM+t];
        w1p[t*4+2] = w1g[2*HDIM+t];
        w1p[t*4+3] = b1[b*HDIM+t];
        b2L[t] = b2[b*HDIM+t];
    } else {
        int idx = t - 128;
        if (idx < 64) bc1L[idx] = bc1[b*64 + idx];
        else {
            int i2 = idx - 64;
            wc2L[i2]       = Wc2[b*192 + i2];
            wc2L[i2+64]    = Wc2[b*192 + i2+64];
            wc2L[i2+128]   = Wc2[b*192 + i2+128];
        }
    }
    if (t < EMB) embL[t] = app_emb[((size_t)b*NAPP + aidr)*EMB + t];
    if (t == 16) bdL = bd[b];
    if (t >= 20 && t < 23) bc2L[t-20] = bc2[b*3 + (t-20)];
    __syncthreads();     // real barrier: cross-wave staging -> compute

    const unsigned short* w2p  = wsu + (size_t)b*BLK_SZ;
    const unsigned short* wfdp = w2p + W2P_SZ;
    const unsigned short* wc1p = wfdp + WFDP_SZ;
    unsigned short* slab = SLAB + wave*4096;
    const f32x4 zero4 = {0.f, 0.f, 0.f, 0.f};

    for (int p = 0; p < 2; p++) {
        const int sbase = wave*64 + p*32;

        // ---- A-frags of H1 in registers (rows = samples sbase + mt*16 + lr) ----
        float pxm[2], pym[2], pzm[2];
        #pragma unroll
        for (int mt = 0; mt < 2; mt++) {
            int s = sbase + mt*16 + lr;
            float ts = nearr + STEPF*(float)s;
            pxm[mt] = ox + ts*dx; pym[mt] = oy + ts*dy; pzm[mt] = oz + ts*dz;
        }
        bh8 afrag[2][4];
        #pragma unroll
        for (int mt = 0; mt < 2; mt++)
        #pragma unroll
        for (int k0 = 0; k0 < 4; k0++)
        #pragma unroll
        for (int bb = 0; bb < 8; bb++) {
            int i = k0*32 + 8*lq + bb;
            float4 w = ((const float4*)w1p)[i];
            float v = fmaf(pxm[mt], w.x, fmaf(pym[mt], w.y, fmaf(pzm[mt], w.z, w.w)));
            afrag[mt][k0][bb] = (short)f2bf(fmaxf(v, 0.f));
        }

        // ---- GEMM1: H2[32][128] = relu(H1 . W2 + b2), in TWO nt-halves ----
        #pragma unroll
        for (int h = 0; h < 2; h++) {
            f32x4 acc1[2][4];
            #pragma unroll
            for (int mt = 0; mt < 2; mt++)
            #pragma unroll
            for (int n4 = 0; n4 < 4; n4++) acc1[mt][n4] = zero4;
            #pragma unroll
            for (int n4 = 0; n4 < 4; n4++) {
                int nt = h*4 + n4;
                bh8 bf0 = ((const bh8*)w2p)[(nt*4+0)*64 + l];
                bh8 bf1 = ((const bh8*)w2p)[(nt*4+1)*64 + l];
                bh8 bf2 = ((const bh8*)w2p)[(nt*4+2)*64 + l];
                bh8 bf3 = ((const bh8*)w2p)[(nt*4+3)*64 + l];
                #pragma unroll
                for (int mt = 0; mt < 2; mt++) {
                    acc1[mt][n4] = __builtin_amdgcn_mfma_f32_16x16x32_bf16(afrag[mt][0], bf0, acc1[mt][n4], 0,0,0);
                    acc1[mt][n4] = __builtin_amdgcn_mfma_f32_16x16x32_bf16(afrag[mt][1], bf1, acc1[mt][n4], 0,0,0);
                    acc1[mt][n4] = __builtin_amdgcn_mfma_f32_16x16x32_bf16(afrag[mt][2], bf2, acc1[mt][n4], 0,0,0);
                    acc1[mt][n4] = __builtin_amdgcn_mfma_f32_16x16x32_bf16(afrag[mt][3], bf3, acc1[mt][n4], 0,0,0);
                }
            }
            // epilogue for this half -> H2 slab (swizzled)
            #pragma unroll
            for (int mt = 0; mt < 2; mt++)
            #pragma unroll
            for (int n4 = 0; n4 < 4; n4++) {
                int col = (h*4 + n4)*16 + lr;
                float bb2 = b2L[col];
                #pragma unroll
                for (int reg = 0; reg < 4; reg++) {
                    int sl = mt*16 + lq*4 + reg;
                    float v = fmaxf(acc1[mt][n4][reg] + bb2, 0.f);
                    int g2 = (col >> 3) ^ (sl & 7);
                    slab[sl*128 + (g2<<3) + (col & 7)] = f2bf(v);
                }
            }
            __builtin_amdgcn_sched_barrier(0);   // keep halves' register pressure separate
        }
        WAVE_FENCE();

        // ---- extract A-frags of H2 into registers (frees the slab for CIN) ----
        bh8 afr2[2][4];
        #pragma unroll
        for (int mt = 0; mt < 2; mt++)
        #pragma unroll
        for (int k0 = 0; k0 < 4; k0++) {
            int sl = mt*16 + lr;
            int g2 = (k0*4 + lq) ^ (sl & 7);
            afr2[mt][k0] = *(const bh8*)&slab[sl*128 + (g2<<3)];
        }
        WAVE_FENCE();   // all slab reads complete before CIN overwrites

        // ---- GEMM2: [feat(32) | sigma | pad] = H2 . [Wf|Wd|0] ----
        f32x4 acc2[2][3];
        #pragma unroll
        for (int mt = 0; mt < 2; mt++)
        #pragma unroll
        for (int nt = 0; nt < 3; nt++) acc2[mt][nt] = zero4;
        #pragma unroll
        for (int nt = 0; nt < 3; nt++) {
            bh8 bf0 = ((const bh8*)wfdp)[(nt*4+0)*64 + l];
            bh8 bf1 = ((const bh8*)wfdp)[(nt*4+1)*64 + l];
            bh8 bf2 = ((const bh8*)wfdp)[(nt*4+2)*64 + l];
            bh8 bf3 = ((const bh8*)wfdp)[(nt*4+3)*64 + l];
            #pragma unroll
            for (int mt = 0; mt < 2; mt++) {
                acc2[mt][nt] = __builtin_amdgcn_mfma_f32_16x16x32_bf16(afr2[mt][0], bf0, acc2[mt][nt], 0,0,0);
                acc2[mt][nt] = __builtin_amdgcn_mfma_f32_16x16x32_bf16(afr2[mt][1], bf1, acc2[mt][nt], 0,0,0);
                acc2[mt][nt] = __builtin_amdgcn_mfma_f32_16x16x32_bf16(afr2[mt][2], bf2, acc2[mt][nt], 0,0,0);
                acc2[mt][nt] = __builtin_amdgcn_mfma_f32_16x16x32_bf16(afr2[mt][3], bf3, acc2[mt][nt], 0,0,0);
            }
        }
        // sigma (col 32 = ntile2,col0): softplus * wv -> partial store
        if (lr == 0) {
            #pragma unroll
            for (int mt = 0; mt < 2; mt++)
            #pragma unroll
            for (int reg = 0; reg < 4; reg++) {
                int sg = sbase + mt*16 + lq*4 + reg;
                float x = acc2[mt][2][reg] + bdL;
                float sgm = log1pf(expf(-fabsf(x))) + fmaxf(x, 0.f);
                tdg[sg] = sgm * wvL[sg];
            }
        }
        // feat -> CIN slab cols 0..31 (swizzled, row stride 64)
        #pragma unroll
        for (int mt = 0; mt < 2; mt++)
        #pragma unroll
        for (int nt = 0; nt < 2; nt++) {
            int f = nt*16 + lr;
            #pragma unroll
            for (int reg = 0; reg < 4; reg++) {
                int sl = mt*16 + lq*4 + reg;
                int g2 = (f >> 3) ^ (sl & 7);
                slab[sl*64 + (g2<<3) + (f & 7)] = f2bf(acc2[mt][nt][reg]);
            }
        }
        // CIN extras cols 32..63 = [d(3), emb(16), exp(1), 0-pad]
        {
            int sl = l & 31, cg = l >> 5;
            #pragma unroll
            for (int j = 0; j < 16; j++) {
                int c = 32 + cg*16 + j;
                float v;
                if (c < 35)       v = (c==32 ? dx : (c==33 ? dy : dz));
                else if (c < 51)  v = embL[c-35];
                else if (c == 51) v = expv;
                else              v = 0.f;
                int g2 = (c >> 3) ^ (sl & 7);
                slab[sl*64 + (g2<<3) + (c & 7)] = f2bf(v);
            }
        }
        WAVE_FENCE();

        // ---- GEMM3: HC[32][64] = relu(CIN . Wc1 + bc1) ----
        bh8 afr3[2][2];
        #pragma unroll
        for (int mt = 0; mt < 2; mt++)
        #pragma unroll
        for (int k0 = 0; k0 < 2; k0++) {
            int sl = mt*16 + lr;
            int g2 = (k0*4 + lq) ^ (sl & 7);
            afr3[mt][k0] = *(const bh8*)&slab[sl*64 + (g2<<3)];
        }
        f32x4 acc3[2][4];
        #pragma unroll
        for (int mt = 0; mt < 2; mt++)
        #pragma unroll
        for (int nt = 0; nt < 4; nt++) acc3[mt][nt] = zero4;
        #pragma unroll
        for (int nt = 0; nt < 4; nt++) {
            bh8 bf0 = ((const bh8*)wc1p)[(nt*2+0)*64 + l];
            bh8 bf1 = ((const bh8*)wc1p)[(nt*2+1)*64 + l];
            #pragma unroll
            for (int mt = 0; mt < 2; mt++) {
                acc3[mt][nt] = __builtin_amdgcn_mfma_f32_16x16x32_bf16(afr3[mt][0], bf0, acc3[mt][nt], 0,0,0);
                acc3[mt][nt] = __builtin_amdgcn_mfma_f32_16x16x32_bf16(afr3[mt][1], bf1, acc3[mt][nt], 0,0,0);
            }
        }
        // color: hc=relu(+bc1); dot wc2; 16-lane reduce; sigmoid * wv -> partial store
        #pragma unroll
        for (int mt = 0; mt < 2; mt++)
        #pragma unroll
        for (int reg = 0; reg < 4; reg++) {
            float p0 = 0.f, p1 = 0.f, p2 = 0.f;
            #pragma unroll
            for (int nt = 0; nt < 4; nt++) {
                int e = nt*16 + lr;
                float hc = fmaxf(acc3[mt][nt][reg] + bc1L[e], 0.f);
                p0 = fmaf(hc, wc2L[e*3+0], p0);
                p1 = fmaf(hc, wc2L[e*3+1], p1);
                p2 = fmaf(hc, wc2L[e*3+2], p2);
            }
            #pragma unroll
            for (int m = 1; m < 16; m <<= 1) {
                p0 += __shfl_xor(p0, m);
                p1 += __shfl_xor(p1, m);
                p2 += __shfl_xor(p2, m);
            }
            if (lr == 0) {
                int sg = sbase + mt*16 + lq*4 + reg;
                float wvv = wvL[sg];
                c0g[sg] = wvv / (1.f + expf(-(p0 + bc2L[0])));
                c1g[sg] = wvv / (1.f + expf(-(p1 + bc2L[1])));
                c2g[sg] = wvv / (1.f + expf(-(p2 + bc2L[2])));
            }
        }
        WAVE_FENCE();   // slab WAR before next pass overwrites
    }
}

// ---------------- composite: sum k-partials, sequential scan ----------------
__global__ __launch_bounds__(256) void comp_kernel(
    const float* __restrict__ ro, const float* __restrict__ rd,
    const float* __restrict__ nearp, const float* __restrict__ farp,
    const int* __restrict__ selw, const float* __restrict__ cselw,
    const float* __restrict__ tdp, const float* __restrict__ c0p,
    const float* __restrict__ c1p, const float* __restrict__ c2p,
    float* __restrict__ out)
{
    const int r = blockIdx.x, t = threadIdx.x;
    __shared__ int selLds[KSEL];
    __shared__ float cselLds[KSEL*3];
    __shared__ float aLds[SNUM], cn0[SNUM], cn1[SNUM], cn2[SNUM];
    if (t < KSEL) selLds[t] = selw[r*KSEL + t];
    if (t < KSEL*3) cselLds[t] = cselw[r*KSEL*3 + t];
    __syncthreads();
    const float ox = ro[r*3], oy = ro[r*3+1], oz = ro[r*3+2];
    const float dx = rd[r*3], dy = rd[r*3+1], dz = rd[r*3+2];
    const float nearr = nearp[r];
    {
        const int s = t;
        float ts = nearr + STEPF*(float)s;
        float px = ox + ts*dx, py = oy + ts*dy, pz = oz + ts*dz;
        float invv[KSEL]; float wsum = 0.f;
        #pragma unroll
        for (int k2 = 0; k2 < KSEL; k2++) {
            float inv = 0.f;
            if (selLds[k2] >= 0) {
                float ex = px - cselLds[k2*3], ey = py - cselLds[k2*3+1], ez = pz - cselLds[k2*3+2];
                inv = 1.f / (sqrtf(ex*ex + ey*ey + ez*ez) + 1e-6f);
            }
            invv[k2] = inv; wsum += inv;
        }
        float tw = 0.f;
        #pragma unroll
        for (int k2 = 0; k2 < KSEL; k2++) {
            float w = (wsum > 0.f) ? invv[k2] / fmaxf(wsum, 1e-12f) : 0.f;
            if (w >= VIS_T && selLds[k2] >= 0) tw += w;
        }
        float td = 0.f, c0 = 0.f, c1 = 0.f, c2 = 0.f;
        #pragma unroll
        for (int k2 = 0; k2 < KSEL; k2++) {
            size_t gg = (size_t)(r*KSEL + k2)*SNUM + s;
            td += tdp[gg]; c0 += c0p[gg]; c1 += c1p[gg]; c2 += c2p[gg];
        }
        float a = fminf(fmaxf(1.f - expf(-td*STEPF), 0.f), 1.f);
        if (tw > 0.f) {
            float dv = fmaxf(tw, 1e-12f);
            c0 /= dv; c1 /= dv; c2 /= dv;
        }
        aLds[s] = a; cn0[s] = c0; cn1[s] = c1; cn2[s] = c2;
    }
    __syncthreads();
    if (t == 0) {
        const float farr = farp[r];
        float T = 1.f, acc = 0.f, rgb0=0.f, rgb1=0.f, rgb2=0.f, dep=0.f;
        for (int s = 0; s < SNUM; s++) {
            float ts = nearr + STEPF*(float)s;
            bool alive = (ts < farr) && (T > T_EPS) && (acc <= TERM_T);
            float a = aLds[s];
            float wgt = alive ? T*a : 0.f;
            rgb0 += wgt*cn0[s]; rgb1 += wgt*cn1[s]; rgb2 += wgt*cn2[s];
            acc += wgt;
            dep += wgt*ts;
            T *= alive ? (1.f - a) : 1.f;
        }
        float depth = dep / fmaxf(acc, 1e-6f);
        out[r*3+0] = rgb0;
        out[r*3+1] = rgb1;
        out[r*3+2] = rgb2;
        out[RNUM*3 + r]        = depth;
        out[RNUM*3 + RNUM + r] = acc;
    }
}

extern "C" void kernel_launch(void* const* d_in, const int* in_sizes, int n_in,
                              void* d_out, int out_size, void* d_ws, size_t ws_size,
                              hipStream_t stream) {
    const float* ro    = (const float*)d_in[0];
    const float* rd    = (const float*)d_in[1];
    const float* bc    = (const float*)d_in[2];
    const float* br    = (const float*)d_in[3];
    const int*   aidp  = (const int*)d_in[4];
    const float* expo  = (const float*)d_in[5];
    const float* nearp = (const float*)d_in[6];
    const float* farp  = (const float*)d_in[7];
    const float* W1    = (const float*)d_in[8];
    const float* b1    = (const float*)d_in[9];
    const float* W2    = (const float*)d_in[10];
    const float* b2    = (const float*)d_in[11];
    const float* Wd    = (const float*)d_in[12];
    const float* bd    = (const float*)d_in[13];
    const float* Wf    = (const float*)d_in[14];
    const float* Wc1   = (const float*)d_in[15];
    const float* bc1   = (const float*)d_in[16];
    const float* Wc2   = (const float*)d_in[17];
    const float* bc2   = (const float*)d_in[18];
    const float* appe  = (const float*)d_in[19];
    float* outp = (float*)d_out;

    // workspace layout (float units from base)
    float* wsf = (float*)d_ws;
    unsigned short* wsu = (unsigned short*)d_ws;          // 64*26624 ush = 3,407,872 B
    int*   selw  = (int*)  (wsf + 851968);                // 2048 ints
    float* cselw =         wsf + 854016;                  // 6144 f32
    float* tdp   =         wsf + 860160;                  // 2048*256
    float* c0p   =         tdp + 2048*SNUM;
    float* c1p   =         c0p + 2048*SNUM;
    float* c2p   =         c1p + 2048*SNUM;               // end ~11.83 MB

    pack_kernel<<<NB, 256, 0, stream>>>(W2, Wf, Wd, Wc1, wsu);
    sel_kernel<<<RNUM, 64, 0, stream>>>(ro, rd, bc, br, selw, cselw);
    mlp_kernel<<<RNUM*KSEL, 256, 0, stream>>>(ro, rd, nearp, expo, aidp,
                                              W1, b1, b2, bd, bc1, Wc2, bc2, appe,
                                              wsu, selw, cselw, tdp, c0p, c1p, c2p);
    comp_kernel<<<RNUM, 256, 0, stream>>>(ro, rd, nearp, farp, selw, cselw,
                                          tdp, c0p, c1p, c2p, outp);
}

// Round 14
// 244.208 us; speedup vs baseline: 1.7317x; 1.3432x over previous
//
#include <hip/hip_runtime.h>

#define RNUM 256
#define NB 64
#define KSEL 8
#define SNUM 256
#define HDIM 128
#define FEAT 32
#define EMB 16
#define NAPP 100
#define CINDIM 52
#define STEPF 0.5f
#define VIS_T 0.01f
#define TERM_T 0.99f
#define T_EPS 1e-4f

// packed-weight sizes (ushort units) per block
#define W2P_SZ   16384      // 8 ntiles * 4 ksteps * 64 lanes * 8
#define WFDP_SZ  6144       // 3 ntiles * 4 ksteps * 64 * 8   (N=48: feat32 | Wd | 0)
#define WC1P_SZ  4096       // 4 ntiles * 2 ksteps * 64 * 8   (K=64: 52 | 0-pad)
#define BLK_SZ   (W2P_SZ + WFDP_SZ + WC1P_SZ)   // 26624 ushorts = 53248 B

typedef __attribute__((ext_vector_type(8))) short bh8;
typedef __attribute__((ext_vector_type(4))) float f32x4;

__device__ __forceinline__ unsigned short f2bf(float f) {
    unsigned int u = __float_as_uint(f);
    unsigned int r = (u + 0x7fffu + ((u >> 16) & 1u)) >> 16;
    return (unsigned short)r;
}

// ---------------- pack: weights -> MFMA B-fragment layout (proven R6) ----------------
__global__ __launch_bounds__(256) void pack_kernel(
    const float* __restrict__ W2, const float* __restrict__ Wf,
    const float* __restrict__ Wd, const float* __restrict__ Wc1,
    unsigned short* __restrict__ wsu)
{
    const int blk = blockIdx.x, t = threadIdx.x;
    unsigned short* w2p  = wsu + (size_t)blk * BLK_SZ;
    unsigned short* wfdp = w2p + W2P_SZ;
    unsigned short* wc1p = w2p + W2P_SZ + WFDP_SZ;
    const float* W2b  = W2  + (size_t)blk * HDIM * HDIM;
    const float* Wfb  = Wf  + (size_t)blk * HDIM * FEAT;
    const float* Wdb  = Wd  + (size_t)blk * HDIM;
    const float* Wc1b = Wc1 + (size_t)blk * CINDIM * 64;

    for (int slot = t; slot < 8*4*64; slot += 256) {
        int unit = slot >> 6, l = slot & 63;
        int n0 = unit >> 2, k0 = unit & 3, q = l >> 4, lr = l & 15;
        bh8 v;
        #pragma unroll
        for (int bb = 0; bb < 8; bb++) {
            int row = k0*32 + 8*q + bb;
            v[bb] = (short)f2bf(W2b[row*HDIM + n0*16 + lr]);
        }
        ((bh8*)w2p)[slot] = v;
    }
    for (int slot = t; slot < 3*4*64; slot += 256) {
        int unit = slot >> 6, l = slot & 63;
        int n0 = unit >> 2, k0 = unit & 3, q = l >> 4, lr = l & 15;
        int gcol = n0*16 + lr;
        bh8 v;
        #pragma unroll
        for (int bb = 0; bb < 8; bb++) {
            int row = k0*32 + 8*q + bb;
            float val = (gcol < FEAT) ? Wfb[row*FEAT + gcol]
                       : ((gcol == FEAT) ? Wdb[row] : 0.f);
            v[bb] = (short)f2bf(val);
        }
        ((bh8*)wfdp)[slot] = v;
    }
    for (int slot = t; slot < 4*2*64; slot += 256) {
        int unit = slot >> 6, l = slot & 63;
        int n0 = unit >> 1, k0 = unit & 1, q = l >> 4, lr = l & 15;
        bh8 v;
        #pragma unroll
        for (int bb = 0; bb < 8; bb++) {
            int row = k0*32 + 8*q + bb;
            float val = (row < CINDIM) ? Wc1b[row*64 + n0*16 + lr] : 0.f;
            v[bb] = (short)f2bf(val);
        }
        ((bh8*)wc1p)[slot] = v;
    }
}

// ---------------- sel: per-ray top-8 block selection (proven R6 logic) ----------------
__global__ __launch_bounds__(64) void sel_kernel(
    const float* __restrict__ ro, const float* __restrict__ rd,
    const float* __restrict__ bc, const float* __restrict__ br,
    int* __restrict__ selw, float* __restrict__ cselw)
{
    const int r = blockIdx.x, t = threadIdx.x;
    __shared__ float distL[NB];
    __shared__ int selLds[KSEL];
    const float ox = ro[r*3], oy = ro[r*3+1], oz = ro[r*3+2];
    const float dx = rd[r*3], dy = rd[r*3+1], dz = rd[r*3+2];
    {
        const int nb = t;
        float a = dx*dx + dy*dy + dz*dz;
        float cx = bc[nb*3], cy = bc[nb*3+1], cz = bc[nb*3+2];
        float rad = br[nb];
        float ocx = ox-cx, ocy = oy-cy, ocz = oz-cz;
        float bq = 2.f*(ocx*dx + ocy*dy + ocz*dz);
        float cq = ocx*ocx + ocy*ocy + ocz*ocz - rad*rad;
        float disc = bq*bq - 4.f*a*cq;
        float sq = disc > 0.f ? sqrtf(disc) : (disc >= 0.f ? 1.f : 0.f);
        float t1 = (-bq - sq) / (2.f*a);
        float t2 = (-bq + sq) / (2.f*a);
        float th = t1 > 0.f ? t1 : t2;
        bool valid = (disc >= 0.f) && (th > 0.f);
        float hx = ox + th*dx - cx, hy = oy + th*dy - cy, hz = oz + th*dz - cz;
        distL[nb] = valid ? sqrtf(hx*hx + hy*hy + hz*hz) : INFINITY;
    }
    __syncthreads();
    if (t == 0) {
        for (int kk = 0; kk < KSEL; kk++) {
            float bd2 = INFINITY; int bi = -1;
            for (int j = 0; j < NB; j++) { if (distL[j] < bd2) { bd2 = distL[j]; bi = j; } }
            selLds[kk] = bi;
            if (bi >= 0) distL[bi] = INFINITY;
        }
    }
    __syncthreads();
    if (t < KSEL) selw[r*KSEL + t] = selLds[t];
    if (t < KSEL*3) {
        int kk = t/3, j = t%3;
        int b = selLds[kk];
        cselw[r*KSEL*3 + t] = (b >= 0) ? bc[b*3+j] : 0.f;
    }
}

// ---------------- mlp: one WG per (ray, k-slot); 4 waves x 64 samples ----------------
// R14: verbatim restore of the R9 configuration — the ONLY proven-clean state:
// plain __launch_bounds__(256) (256-reg tier, no spill: WRITE_SIZE = 8.5 MB
// partials exactly), nt-halved GEMM1 (caps live acc at 32 VGPR/half), real
// __syncthreads phase fences (they double as regalloc fences; every removal
// or cap variant spilled: R7/R10/R11/R12/R13 all hit 300-420us scratch modes).
// Measured: 244.8us total, mlp 215us, VGPR 256, Occ 6.6%.
__global__ __launch_bounds__(256) void mlp_kernel(
    const float* __restrict__ ro, const float* __restrict__ rd,
    const float* __restrict__ nearp, const float* __restrict__ expo,
    const int* __restrict__ aid,
    const float* __restrict__ W1, const float* __restrict__ b1,
    const float* __restrict__ b2, const float* __restrict__ bd,
    const float* __restrict__ bc1, const float* __restrict__ Wc2,
    const float* __restrict__ bc2, const float* __restrict__ app_emb,
    const unsigned short* __restrict__ wsu,
    const int* __restrict__ selw, const float* __restrict__ cselw,
    float* __restrict__ tdp, float* __restrict__ c0p,
    float* __restrict__ c1p, float* __restrict__ c2p)
{
    const int g = blockIdx.x, r = g >> 3, kk = g & 7, t = threadIdx.x;
    const int wave = t >> 6, l = t & 63, lq = l >> 4, lr = l & 15;

    __shared__ int   selLds[KSEL];
    __shared__ float cselLds[KSEL*3];
    __shared__ float wvL[SNUM];
    __shared__ __align__(16) float w1p[HDIM*4];     // (w1x,w1y,w1z,b1)
    __shared__ float b2L[HDIM], bc1L[64], wc2L[192], bc2L[3], embL[EMB];
    __shared__ float bdL;
    // per-wave 4096-ushort slab: H2 tile [32][128]; CIN tile [32][64] aliases it
    __shared__ __align__(16) unsigned short SLAB[4*4096];   // 32 KB

    float* tdg = tdp + (size_t)g * SNUM;
    float* c0g = c0p + (size_t)g * SNUM;
    float* c1g = c1p + (size_t)g * SNUM;
    float* c2g = c2p + (size_t)g * SNUM;

    if (t < KSEL) selLds[t] = selw[r*KSEL + t];
    if (t < KSEL*3) cselLds[t] = cselw[r*KSEL*3 + t];
    __syncthreads();
    const int b = selLds[kk];
    if (b < 0) {     // uniform: zero partials, exit
        tdg[t] = 0.f; c0g[t] = 0.f; c1g[t] = 0.f; c2g[t] = 0.f;
        return;
    }

    const float ox = ro[r*3], oy = ro[r*3+1], oz = ro[r*3+2];
    const float dx = rd[r*3], dy = rd[r*3+1], dz = rd[r*3+2];
    const float nearr = nearp[r];
    const float expv  = expo[r];
    const int   aidr  = aid[r];

    // per-sample wv for this kk (same formula as proven wv_at)
    {
        const int s = t;
        float ts = nearr + STEPF*(float)s;
        float px = ox + ts*dx, py = oy + ts*dy, pz = oz + ts*dz;
        float wsum = 0.f, invk = 0.f;
        #pragma unroll
        for (int k2 = 0; k2 < KSEL; k2++) {
            if (selLds[k2] >= 0) {
                float ex = px - cselLds[k2*3], ey = py - cselLds[k2*3+1], ez = pz - cselLds[k2*3+2];
                float inv = 1.f / (sqrtf(ex*ex + ey*ey + ez*ez) + 1e-6f);
                wsum += inv;
                if (k2 == kk) invk = inv;
            }
        }
        float w = (wsum > 0.f) ? invk / fmaxf(wsum, 1e-12f) : 0.f;
        wvL[s] = (w >= VIS_T) ? w : 0.f;
    }
    // small vectors
    if (t < HDIM) {
        const float* w1g = W1 + (size_t)b*3*HDIM;
        w1p[t*4+0] = w1g[t];
        w1p[t*4+1] = w1g[HDIM+t];
        w1p[t*4+2] = w1g[2*HDIM+t];
        w1p[t*4+3] = b1[b*HDIM+t];
        b2L[t] = b2[b*HDIM+t];
    } else {
        int idx = t - 128;
        if (idx < 64) bc1L[idx] = bc1[b*64 + idx];
        else {
            int i2 = idx - 64;
            wc2L[i2]       = Wc2[b*192 + i2];
            wc2L[i2+64]    = Wc2[b*192 + i2+64];
            wc2L[i2+128]   = Wc2[b*192 + i2+128];
        }
    }
    if (t < EMB) embL[t] = app_emb[((size_t)b*NAPP + aidr)*EMB + t];
    if (t == 16) bdL = bd[b];
    if (t >= 20 && t < 23) bc2L[t-20] = bc2[b*3 + (t-20)];
    __syncthreads();

    const unsigned short* w2p  = wsu + (size_t)b*BLK_SZ;
    const unsigned short* wfdp = w2p + W2P_SZ;
    const unsigned short* wc1p = wfdp + WFDP_SZ;
    unsigned short* slab = SLAB + wave*4096;
    const f32x4 zero4 = {0.f, 0.f, 0.f, 0.f};

    for (int p = 0; p < 2; p++) {
        const int sbase = wave*64 + p*32;

        // ---- A-frags of H1 in registers (rows = samples sbase + mt*16 + lr) ----
        float pxm[2], pym[2], pzm[2];
        #pragma unroll
        for (int mt = 0; mt < 2; mt++) {
            int s = sbase + mt*16 + lr;
            float ts = nearr + STEPF*(float)s;
            pxm[mt] = ox + ts*dx; pym[mt] = oy + ts*dy; pzm[mt] = oz + ts*dz;
        }
        bh8 afrag[2][4];
        #pragma unroll
        for (int mt = 0; mt < 2; mt++)
        #pragma unroll
        for (int k0 = 0; k0 < 4; k0++)
        #pragma unroll
        for (int bb = 0; bb < 8; bb++) {
            int i = k0*32 + 8*lq + bb;
            float4 w = ((const float4*)w1p)[i];
            float v = fmaf(pxm[mt], w.x, fmaf(pym[mt], w.y, fmaf(pzm[mt], w.z, w.w)));
            afrag[mt][k0][bb] = (short)f2bf(fmaxf(v, 0.f));
        }

        // ---- GEMM1: H2[32][128] = relu(H1 . W2 + b2), in TWO nt-halves ----
        // (caps live accumulators at acc1[2][4] = 32 VGPRs per half; the full
        //  acc1[2][8] + hoisted loads hit the 256-VGPR cap and spilled 65 MB)
        #pragma unroll
        for (int h = 0; h < 2; h++) {
            f32x4 acc1[2][4];
            #pragma unroll
            for (int mt = 0; mt < 2; mt++)
            #pragma unroll
            for (int n4 = 0; n4 < 4; n4++) acc1[mt][n4] = zero4;
            #pragma unroll
            for (int n4 = 0; n4 < 4; n4++) {
                int nt = h*4 + n4;
                bh8 bf0 = ((const bh8*)w2p)[(nt*4+0)*64 + l];
                bh8 bf1 = ((const bh8*)w2p)[(nt*4+1)*64 + l];
                bh8 bf2 = ((const bh8*)w2p)[(nt*4+2)*64 + l];
                bh8 bf3 = ((const bh8*)w2p)[(nt*4+3)*64 + l];
                #pragma unroll
                for (int mt = 0; mt < 2; mt++) {
                    acc1[mt][n4] = __builtin_amdgcn_mfma_f32_16x16x32_bf16(afrag[mt][0], bf0, acc1[mt][n4], 0,0,0);
                    acc1[mt][n4] = __builtin_amdgcn_mfma_f32_16x16x32_bf16(afrag[mt][1], bf1, acc1[mt][n4], 0,0,0);
                    acc1[mt][n4] = __builtin_amdgcn_mfma_f32_16x16x32_bf16(afrag[mt][2], bf2, acc1[mt][n4], 0,0,0);
                    acc1[mt][n4] = __builtin_amdgcn_mfma_f32_16x16x32_bf16(afrag[mt][3], bf3, acc1[mt][n4], 0,0,0);
                }
            }
            // epilogue for this half -> H2 slab (swizzled)
            #pragma unroll
            for (int mt = 0; mt < 2; mt++)
            #pragma unroll
            for (int n4 = 0; n4 < 4; n4++) {
                int col = (h*4 + n4)*16 + lr;
                float bb2 = b2L[col];
                #pragma unroll
                for (int reg = 0; reg < 4; reg++) {
                    int sl = mt*16 + lq*4 + reg;
                    float v = fmaxf(acc1[mt][n4][reg] + bb2, 0.f);
                    int g2 = (col >> 3) ^ (sl & 7);
                    slab[sl*128 + (g2<<3) + (col & 7)] = f2bf(v);
                }
            }
            __builtin_amdgcn_sched_barrier(0);   // keep halves' register pressure separate
        }
        __syncthreads();

        // ---- extract A-frags of H2 into registers (frees the slab for CIN) ----
        bh8 afr2[2][4];
        #pragma unroll
        for (int mt = 0; mt < 2; mt++)
        #pragma unroll
        for (int k0 = 0; k0 < 4; k0++) {
            int sl = mt*16 + lr;
            int g2 = (k0*4 + lq) ^ (sl & 7);
            afr2[mt][k0] = *(const bh8*)&slab[sl*128 + (g2<<3)];
        }
        __syncthreads();   // lgkm drain: all slab reads complete before CIN overwrites

        // ---- GEMM2: [feat(32) | sigma | pad] = H2 . [Wf|Wd|0] ----
        f32x4 acc2[2][3];
        #pragma unroll
        for (int mt = 0; mt < 2; mt++)
        #pragma unroll
        for (int nt = 0; nt < 3; nt++) acc2[mt][nt] = zero4;
        #pragma unroll
        for (int nt = 0; nt < 3; nt++) {
            bh8 bf0 = ((const bh8*)wfdp)[(nt*4+0)*64 + l];
            bh8 bf1 = ((const bh8*)wfdp)[(nt*4+1)*64 + l];
            bh8 bf2 = ((const bh8*)wfdp)[(nt*4+2)*64 + l];
            bh8 bf3 = ((const bh8*)wfdp)[(nt*4+3)*64 + l];
            #pragma unroll
            for (int mt = 0; mt < 2; mt++) {
                acc2[mt][nt] = __builtin_amdgcn_mfma_f32_16x16x32_bf16(afr2[mt][0], bf0, acc2[mt][nt], 0,0,0);
                acc2[mt][nt] = __builtin_amdgcn_mfma_f32_16x16x32_bf16(afr2[mt][1], bf1, acc2[mt][nt], 0,0,0);
                acc2[mt][nt] = __builtin_amdgcn_mfma_f32_16x16x32_bf16(afr2[mt][2], bf2, acc2[mt][nt], 0,0,0);
                acc2[mt][nt] = __builtin_amdgcn_mfma_f32_16x16x32_bf16(afr2[mt][3], bf3, acc2[mt][nt], 0,0,0);
            }
        }
        // sigma (col 32 = ntile2,col0): softplus * wv -> partial store
        if (lr == 0) {
            #pragma unroll
            for (int mt = 0; mt < 2; mt++)
            #pragma unroll
            for (int reg = 0; reg < 4; reg++) {
                int sg = sbase + mt*16 + lq*4 + reg;
                float x = acc2[mt][2][reg] + bdL;
                float sgm = log1pf(expf(-fabsf(x))) + fmaxf(x, 0.f);
                tdg[sg] = sgm * wvL[sg];
            }
        }
        // feat -> CIN slab cols 0..31 (swizzled, row stride 64)
        #pragma unroll
        for (int mt = 0; mt < 2; mt++)
        #pragma unroll
        for (int nt = 0; nt < 2; nt++) {
            int f = nt*16 + lr;
            #pragma unroll
            for (int reg = 0; reg < 4; reg++) {
                int sl = mt*16 + lq*4 + reg;
                int g2 = (f >> 3) ^ (sl & 7);
                slab[sl*64 + (g2<<3) + (f & 7)] = f2bf(acc2[mt][nt][reg]);
            }
        }
        // CIN extras cols 32..63 = [d(3), emb(16), exp(1), 0-pad]
        {
            int sl = l & 31, cg = l >> 5;
            #pragma unroll
            for (int j = 0; j < 16; j++) {
                int c = 32 + cg*16 + j;
                float v;
                if (c < 35)       v = (c==32 ? dx : (c==33 ? dy : dz));
                else if (c < 51)  v = embL[c-35];
                else if (c == 51) v = expv;
                else              v = 0.f;
                int g2 = (c >> 3) ^ (sl & 7);
                slab[sl*64 + (g2<<3) + (c & 7)] = f2bf(v);
            }
        }
        __syncthreads();

        // ---- GEMM3: HC[32][64] = relu(CIN . Wc1 + bc1) ----
        bh8 afr3[2][2];
        #pragma unroll
        for (int mt = 0; mt < 2; mt++)
        #pragma unroll
        for (int k0 = 0; k0 < 2; k0++) {
            int sl = mt*16 + lr;
            int g2 = (k0*4 + lq) ^ (sl & 7);
            afr3[mt][k0] = *(const bh8*)&slab[sl*64 + (g2<<3)];
        }
        f32x4 acc3[2][4];
        #pragma unroll
        for (int mt = 0; mt < 2; mt++)
        #pragma unroll
        for (int nt = 0; nt < 4; nt++) acc3[mt][nt] = zero4;
        #pragma unroll
        for (int nt = 0; nt < 4; nt++) {
            bh8 bf0 = ((const bh8*)wc1p)[(nt*2+0)*64 + l];
            bh8 bf1 = ((const bh8*)wc1p)[(nt*2+1)*64 + l];
            #pragma unroll
            for (int mt = 0; mt < 2; mt++) {
                acc3[mt][nt] = __builtin_amdgcn_mfma_f32_16x16x32_bf16(afr3[mt][0], bf0, acc3[mt][nt], 0,0,0);
                acc3[mt][nt] = __builtin_amdgcn_mfma_f32_16x16x32_bf16(afr3[mt][1], bf1, acc3[mt][nt], 0,0,0);
            }
        }
        // color: hc=relu(+bc1); dot wc2; 16-lane reduce; sigmoid * wv -> partial store
        #pragma unroll
        for (int mt = 0; mt < 2; mt++)
        #pragma unroll
        for (int reg = 0; reg < 4; reg++) {
            float p0 = 0.f, p1 = 0.f, p2 = 0.f;
            #pragma unroll
            for (int nt = 0; nt < 4; nt++) {
                int e = nt*16 + lr;
                float hc = fmaxf(acc3[mt][nt][reg] + bc1L[e], 0.f);
                p0 = fmaf(hc, wc2L[e*3+0], p0);
                p1 = fmaf(hc, wc2L[e*3+1], p1);
                p2 = fmaf(hc, wc2L[e*3+2], p2);
            }
            #pragma unroll
            for (int m = 1; m < 16; m <<= 1) {
                p0 += __shfl_xor(p0, m);
                p1 += __shfl_xor(p1, m);
                p2 += __shfl_xor(p2, m);
            }
            if (lr == 0) {
                int sg = sbase + mt*16 + lq*4 + reg;
                float wvv = wvL[sg];
                c0g[sg] = wvv / (1.f + expf(-(p0 + bc2L[0])));
                c1g[sg] = wvv / (1.f + expf(-(p1 + bc2L[1])));
                c2g[sg] = wvv / (1.f + expf(-(p2 + bc2L[2])));
            }
        }
        __syncthreads();   // protect slab before next pass overwrites
    }
}

// ---------------- composite: sum k-partials, sequential scan ----------------
__global__ __launch_bounds__(256) void comp_kernel(
    const float* __restrict__ ro, const float* __restrict__ rd,
    const float* __restrict__ nearp, const float* __restrict__ farp,
    const int* __restrict__ selw, const float* __restrict__ cselw,
    const float* __restrict__ tdp, const float* __restrict__ c0p,
    const float* __restrict__ c1p, const float* __restrict__ c2p,
    float* __restrict__ out)
{
    const int r = blockIdx.x, t = threadIdx.x;
    __shared__ int selLds[KSEL];
    __shared__ float cselLds[KSEL*3];
    __shared__ float aLds[SNUM], cn0[SNUM], cn1[SNUM], cn2[SNUM];
    if (t < KSEL) selLds[t] = selw[r*KSEL + t];
    if (t < KSEL*3) cselLds[t] = cselw[r*KSEL*3 + t];
    __syncthreads();
    const float ox = ro[r*3], oy = ro[r*3+1], oz = ro[r*3+2];
    const float dx = rd[r*3], dy = rd[r*3+1], dz = rd[r*3+2];
    const float nearr = nearp[r];
    {
        const int s = t;
        float ts = nearr + STEPF*(float)s;
        float px = ox + ts*dx, py = oy + ts*dy, pz = oz + ts*dz;
        float invv[KSEL]; float wsum = 0.f;
        #pragma unroll
        for (int k2 = 0; k2 < KSEL; k2++) {
            float inv = 0.f;
            if (selLds[k2] >= 0) {
                float ex = px - cselLds[k2*3], ey = py - cselLds[k2*3+1], ez = pz - cselLds[k2*3+2];
                inv = 1.f / (sqrtf(ex*ex + ey*ey + ez*ez) + 1e-6f);
            }
            invv[k2] = inv; wsum += inv;
        }
        float tw = 0.f;
        #pragma unroll
        for (int k2 = 0; k2 < KSEL; k2++) {
            float w = (wsum > 0.f) ? invv[k2] / fmaxf(wsum, 1e-12f) : 0.f;
            if (w >= VIS_T && selLds[k2] >= 0) tw += w;
        }
        float td = 0.f, c0 = 0.f, c1 = 0.f, c2 = 0.f;
        #pragma unroll
        for (int k2 = 0; k2 < KSEL; k2++) {
            size_t gg = (size_t)(r*KSEL + k2)*SNUM + s;
            td += tdp[gg]; c0 += c0p[gg]; c1 += c1p[gg]; c2 += c2p[gg];
        }
        float a = fminf(fmaxf(1.f - expf(-td*STEPF), 0.f), 1.f);
        if (tw > 0.f) {
            float dv = fmaxf(tw, 1e-12f);
            c0 /= dv; c1 /= dv; c2 /= dv;
        }
        aLds[s] = a; cn0[s] = c0; cn1[s] = c1; cn2[s] = c2;
    }
    __syncthreads();
    if (t == 0) {
        const float farr = farp[r];
        float T = 1.f, acc = 0.f, rgb0=0.f, rgb1=0.f, rgb2=0.f, dep=0.f;
        for (int s = 0; s < SNUM; s++) {
            float ts = nearr + STEPF*(float)s;
            bool alive = (ts < farr) && (T > T_EPS) && (acc <= TERM_T);
            float a = aLds[s];
            float wgt = alive ? T*a : 0.f;
            rgb0 += wgt*cn0[s]; rgb1 += wgt*cn1[s]; rgb2 += wgt*cn2[s];
            acc += wgt;
            dep += wgt*ts;
            T *= alive ? (1.f - a) : 1.f;
        }
        float depth = dep / fmaxf(acc, 1e-6f);
        out[r*3+0] = rgb0;
        out[r*3+1] = rgb1;
        out[r*3+2] = rgb2;
        out[RNUM*3 + r]        = depth;
        out[RNUM*3 + RNUM + r] = acc;
    }
}

extern "C" void kernel_launch(void* const* d_in, const int* in_sizes, int n_in,
                              void* d_out, int out_size, void* d_ws, size_t ws_size,
                              hipStream_t stream) {
    const float* ro    = (const float*)d_in[0];
    const float* rd    = (const float*)d_in[1];
    const float* bc    = (const float*)d_in[2];
    const float* br    = (const float*)d_in[3];
    const int*   aidp  = (const int*)d_in[4];
    const float* expo  = (const float*)d_in[5];
    const float* nearp = (const float*)d_in[6];
    const float* farp  = (const float*)d_in[7];
    const float* W1    = (const float*)d_in[8];
    const float* b1    = (const float*)d_in[9];
    const float* W2    = (const float*)d_in[10];
    const float* b2    = (const float*)d_in[11];
    const float* Wd    = (const float*)d_in[12];
    const float* bd    = (const float*)d_in[13];
    const float* Wf    = (const float*)d_in[14];
    const float* Wc1   = (const float*)d_in[15];
    const float* bc1   = (const float*)d_in[16];
    const float* Wc2   = (const float*)d_in[17];
    const float* bc2   = (const float*)d_in[18];
    const float* appe  = (const float*)d_in[19];
    float* outp = (float*)d_out;

    // workspace layout (float units from base)
    float* wsf = (float*)d_ws;
    unsigned short* wsu = (unsigned short*)d_ws;          // 64*26624 ush = 3,407,872 B
    int*   selw  = (int*)  (wsf + 851968);                // 2048 ints
    float* cselw =         wsf + 854016;                  // 6144 f32
    float* tdp   =         wsf + 860160;                  // 2048*256
    float* c0p   =         tdp + 2048*SNUM;
    float* c1p   =         c0p + 2048*SNUM;
    float* c2p   =         c1p + 2048*SNUM;               // end ~11.83 MB

    pack_kernel<<<NB, 256, 0, stream>>>(W2, Wf, Wd, Wc1, wsu);
    sel_kernel<<<RNUM, 64, 0, stream>>>(ro, rd, bc, br, selw, cselw);
    mlp_kernel<<<RNUM*KSEL, 256, 0, stream>>>(ro, rd, nearp, expo, aidp,
                                              W1, b1, b2, bd, bc1, Wc2, bc2, appe,
                                              wsu, selw, cselw, tdp, c0p, c1p, c2p);
    comp_kernel<<<RNUM, 256, 0, stream>>>(ro, rd, nearp, farp, selw, cselw,
                                          tdp, c0p, c1p, c2p, outp);
}

// Round 15
// 238.627 us; speedup vs baseline: 1.7722x; 1.0234x over previous
//
#include <hip/hip_runtime.h>

#define RNUM 256
#define NB 64
#define KSEL 8
#define SNUM 256
#define HDIM 128
#define FEAT 32
#define EMB 16
#define NAPP 100
#define CINDIM 52
#define STEPF 0.5f
#define VIS_T 0.01f
#define TERM_T 0.99f
#define T_EPS 1e-4f

// packed-weight sizes (ushort units) per block
#define W2P_SZ   16384      // 8 ntiles * 4 ksteps * 64 lanes * 8
#define WFDP_SZ  6144       // 3 ntiles * 4 ksteps * 64 * 8   (N=48: feat32 | Wd | 0)
#define WC1P_SZ  4096       // 4 ntiles * 2 ksteps * 64 * 8   (K=64: 52 | 0-pad)
#define BLK_SZ   (W2P_SZ + WFDP_SZ + WC1P_SZ)   // 26624 ushorts = 53248 B

typedef __attribute__((ext_vector_type(8))) short bh8;
typedef __attribute__((ext_vector_type(4))) float f32x4;

__device__ __forceinline__ unsigned short f2bf(float f) {
    unsigned int u = __float_as_uint(f);
    unsigned int r = (u + 0x7fffu + ((u >> 16) & 1u)) >> 16;
    return (unsigned short)r;
}

// ---------------- pre: fused pack (4x-parallel) + sel ----------------
// Blocks [0,256): pack quarter (blk>>6 = quarter, blk&63 = weight block) —
// identical per-slot math to the proven R6 pack, index range split 4 ways.
// Blocks [256,512): per-ray top-8 selection (proven R6 logic, t<NB guarded).
// pack and sel are independent (both read only inputs), so fusing them into
// one launch removes a launch gap and runs pack on 4x the CUs.
__global__ __launch_bounds__(256) void pre_kernel(
    const float* __restrict__ ro, const float* __restrict__ rd,
    const float* __restrict__ bc, const float* __restrict__ br,
    const float* __restrict__ W2, const float* __restrict__ Wf,
    const float* __restrict__ Wd, const float* __restrict__ Wc1,
    unsigned short* __restrict__ wsu,
    int* __restrict__ selw, float* __restrict__ cselw)
{
    const int blk = blockIdx.x, t = threadIdx.x;
    if (blk < 4*NB) {
        const int qtr = blk >> 6, b = blk & 63;
        unsigned short* w2p  = wsu + (size_t)b * BLK_SZ;
        unsigned short* wfdp = w2p + W2P_SZ;
        unsigned short* wc1p = w2p + W2P_SZ + WFDP_SZ;
        const float* W2b  = W2  + (size_t)b * HDIM * HDIM;
        const float* Wfb  = Wf  + (size_t)b * HDIM * FEAT;
        const float* Wdb  = Wd  + (size_t)b * HDIM;
        const float* Wc1b = Wc1 + (size_t)b * CINDIM * 64;

        for (int s2 = t; s2 < 512; s2 += 256) {              // W2: 2048 slots / 4
            int slot = qtr*512 + s2;
            int unit = slot >> 6, l = slot & 63;
            int n0 = unit >> 2, k0 = unit & 3, q = l >> 4, lr = l & 15;
            bh8 v;
            #pragma unroll
            for (int bb = 0; bb < 8; bb++) {
                int row = k0*32 + 8*q + bb;
                v[bb] = (short)f2bf(W2b[row*HDIM + n0*16 + lr]);
            }
            ((bh8*)w2p)[slot] = v;
        }
        for (int s2 = t; s2 < 192; s2 += 256) {              // [Wf|Wd|0]: 768 / 4
            int slot = qtr*192 + s2;
            int unit = slot >> 6, l = slot & 63;
            int n0 = unit >> 2, k0 = unit & 3, q = l >> 4, lr = l & 15;
            int gcol = n0*16 + lr;
            bh8 v;
            #pragma unroll
            for (int bb = 0; bb < 8; bb++) {
                int row = k0*32 + 8*q + bb;
                float val = (gcol < FEAT) ? Wfb[row*FEAT + gcol]
                           : ((gcol == FEAT) ? Wdb[row] : 0.f);
                v[bb] = (short)f2bf(val);
            }
            ((bh8*)wfdp)[slot] = v;
        }
        for (int s2 = t; s2 < 128; s2 += 256) {              // Wc1: 512 / 4
            int slot = qtr*128 + s2;
            int unit = slot >> 6, l = slot & 63;
            int n0 = unit >> 1, k0 = unit & 1, q = l >> 4, lr = l & 15;
            bh8 v;
            #pragma unroll
            for (int bb = 0; bb < 8; bb++) {
                int row = k0*32 + 8*q + bb;
                float val = (row < CINDIM) ? Wc1b[row*64 + n0*16 + lr] : 0.f;
                v[bb] = (short)f2bf(val);
            }
            ((bh8*)wc1p)[slot] = v;
        }
    } else {
        const int r = blk - 4*NB;
        __shared__ float distL[NB];
        __shared__ int selLds[KSEL];
        const float ox = ro[r*3], oy = ro[r*3+1], oz = ro[r*3+2];
        const float dx = rd[r*3], dy = rd[r*3+1], dz = rd[r*3+2];
        if (t < NB) {
            const int nb = t;
            float a = dx*dx + dy*dy + dz*dz;
            float cx = bc[nb*3], cy = bc[nb*3+1], cz = bc[nb*3+2];
            float rad = br[nb];
            float ocx = ox-cx, ocy = oy-cy, ocz = oz-cz;
            float bq = 2.f*(ocx*dx + ocy*dy + ocz*dz);
            float cq = ocx*ocx + ocy*ocy + ocz*ocz - rad*rad;
            float disc = bq*bq - 4.f*a*cq;
            // ref quirk: sq = sqrt(where(disc>0, disc, 1.0)); sq = where(disc>=0, sq, 0)
            float sq = disc > 0.f ? sqrtf(disc) : (disc >= 0.f ? 1.f : 0.f);
            float t1 = (-bq - sq) / (2.f*a);
            float t2 = (-bq + sq) / (2.f*a);
            float th = t1 > 0.f ? t1 : t2;
            bool valid = (disc >= 0.f) && (th > 0.f);
            float hx = ox + th*dx - cx, hy = oy + th*dy - cy, hz = oz + th*dz - cz;
            distL[nb] = valid ? sqrtf(hx*hx + hy*hy + hz*hz) : INFINITY;
        }
        __syncthreads();
        if (t == 0) {
            for (int kk = 0; kk < KSEL; kk++) {
                float bd2 = INFINITY; int bi = -1;
                for (int j = 0; j < NB; j++) { if (distL[j] < bd2) { bd2 = distL[j]; bi = j; } }
                selLds[kk] = bi;
                if (bi >= 0) distL[bi] = INFINITY;
            }
        }
        __syncthreads();
        if (t < KSEL) selw[r*KSEL + t] = selLds[t];
        if (t < KSEL*3) {
            int kk = t/3, j = t%3;
            int b = selLds[kk];
            cselw[r*KSEL*3 + t] = (b >= 0) ? bc[b*3+j] : 0.f;
        }
    }
}

// ---------------- mlp: one WG per (ray, k-slot); 4 waves x 64 samples ----------------
// Verbatim R9/R14 configuration — the ONLY proven-clean state: plain
// __launch_bounds__(256) (256-reg tier, no spill: WRITE_SIZE = 8.5 MB partials
// exactly), nt-halved GEMM1 (caps live acc at 32 VGPR/half), real __syncthreads
// phase fences (they double as regalloc fences; every removal or cap variant
// spilled: R7/R10/R11/R12/R13 all hit 300-420us scratch modes).
// Measured: mlp 215us, VGPR 256, Occ 6.6%, MfmaUtil 3%, VALUBusy 24%.
__global__ __launch_bounds__(256) void mlp_kernel(
    const float* __restrict__ ro, const float* __restrict__ rd,
    const float* __restrict__ nearp, const float* __restrict__ expo,
    const int* __restrict__ aid,
    const float* __restrict__ W1, const float* __restrict__ b1,
    const float* __restrict__ b2, const float* __restrict__ bd,
    const float* __restrict__ bc1, const float* __restrict__ Wc2,
    const float* __restrict__ bc2, const float* __restrict__ app_emb,
    const unsigned short* __restrict__ wsu,
    const int* __restrict__ selw, const float* __restrict__ cselw,
    float* __restrict__ tdp, float* __restrict__ c0p,
    float* __restrict__ c1p, float* __restrict__ c2p)
{
    const int g = blockIdx.x, r = g >> 3, kk = g & 7, t = threadIdx.x;
    const int wave = t >> 6, l = t & 63, lq = l >> 4, lr = l & 15;

    __shared__ int   selLds[KSEL];
    __shared__ float cselLds[KSEL*3];
    __shared__ float wvL[SNUM];
    __shared__ __align__(16) float w1p[HDIM*4];     // (w1x,w1y,w1z,b1)
    __shared__ float b2L[HDIM], bc1L[64], wc2L[192], bc2L[3], embL[EMB];
    __shared__ float bdL;
    // per-wave 4096-ushort slab: H2 tile [32][128]; CIN tile [32][64] aliases it
    __shared__ __align__(16) unsigned short SLAB[4*4096];   // 32 KB

    float* tdg = tdp + (size_t)g * SNUM;
    float* c0g = c0p + (size_t)g * SNUM;
    float* c1g = c1p + (size_t)g * SNUM;
    float* c2g = c2p + (size_t)g * SNUM;

    if (t < KSEL) selLds[t] = selw[r*KSEL + t];
    if (t < KSEL*3) cselLds[t] = cselw[r*KSEL*3 + t];
    __syncthreads();
    const int b = selLds[kk];
    if (b < 0) {     // uniform: zero partials, exit
        tdg[t] = 0.f; c0g[t] = 0.f; c1g[t] = 0.f; c2g[t] = 0.f;
        return;
    }

    const float ox = ro[r*3], oy = ro[r*3+1], oz = ro[r*3+2];
    const float dx = rd[r*3], dy = rd[r*3+1], dz = rd[r*3+2];
    const float nearr = nearp[r];
    const float expv  = expo[r];
    const int   aidr  = aid[r];

    // per-sample wv for this kk (same formula as proven wv_at)
    {
        const int s = t;
        float ts = nearr + STEPF*(float)s;
        float px = ox + ts*dx, py = oy + ts*dy, pz = oz + ts*dz;
        float wsum = 0.f, invk = 0.f;
        #pragma unroll
        for (int k2 = 0; k2 < KSEL; k2++) {
            if (selLds[k2] >= 0) {
                float ex = px - cselLds[k2*3], ey = py - cselLds[k2*3+1], ez = pz - cselLds[k2*3+2];
                float inv = 1.f / (sqrtf(ex*ex + ey*ey + ez*ez) + 1e-6f);
                wsum += inv;
                if (k2 == kk) invk = inv;
            }
        }
        float w = (wsum > 0.f) ? invk / fmaxf(wsum, 1e-12f) : 0.f;
        wvL[s] = (w >= VIS_T) ? w : 0.f;
    }
    // small vectors
    if (t < HDIM) {
        const float* w1g = W1 + (size_t)b*3*HDIM;
        w1p[t*4+0] = w1g[t];
        w1p[t*4+1] = w1g[HDIM+t];
        w1p[t*4+2] = w1g[2*HDIM+t];
        w1p[t*4+3] = b1[b*HDIM+t];
        b2L[t] = b2[b*HDIM+t];
    } else {
        int idx = t - 128;
        if (idx < 64) bc1L[idx] = bc1[b*64 + idx];
        else {
            int i2 = idx - 64;
            wc2L[i2]       = Wc2[b*192 + i2];
            wc2L[i2+64]    = Wc2[b*192 + i2+64];
            wc2L[i2+128]   = Wc2[b*192 + i2+128];
        }
    }
    if (t < EMB) embL[t] = app_emb[((size_t)b*NAPP + aidr)*EMB + t];
    if (t == 16) bdL = bd[b];
    if (t >= 20 && t < 23) bc2L[t-20] = bc2[b*3 + (t-20)];
    __syncthreads();

    const unsigned short* w2p  = wsu + (size_t)b*BLK_SZ;
    const unsigned short* wfdp = w2p + W2P_SZ;
    const unsigned short* wc1p = wfdp + WFDP_SZ;
    unsigned short* slab = SLAB + wave*4096;
    const f32x4 zero4 = {0.f, 0.f, 0.f, 0.f};

    for (int p = 0; p < 2; p++) {
        const int sbase = wave*64 + p*32;

        // ---- A-frags of H1 in registers (rows = samples sbase + mt*16 + lr) ----
        float pxm[2], pym[2], pzm[2];
        #pragma unroll
        for (int mt = 0; mt < 2; mt++) {
            int s = sbase + mt*16 + lr;
            float ts = nearr + STEPF*(float)s;
            pxm[mt] = ox + ts*dx; pym[mt] = oy + ts*dy; pzm[mt] = oz + ts*dz;
        }
        bh8 afrag[2][4];
        #pragma unroll
        for (int mt = 0; mt < 2; mt++)
        #pragma unroll
        for (int k0 = 0; k0 < 4; k0++)
        #pragma unroll
        for (int bb = 0; bb < 8; bb++) {
            int i = k0*32 + 8*lq + bb;
            float4 w = ((const float4*)w1p)[i];
            float v = fmaf(pxm[mt], w.x, fmaf(pym[mt], w.y, fmaf(pzm[mt], w.z, w.w)));
            afrag[mt][k0][bb] = (short)f2bf(fmaxf(v, 0.f));
        }

        // ---- GEMM1: H2[32][128] = relu(H1 . W2 + b2), in TWO nt-halves ----
        #pragma unroll
        for (int h = 0; h < 2; h++) {
            f32x4 acc1[2][4];
            #pragma unroll
            for (int mt = 0; mt < 2; mt++)
            #pragma unroll
            for (int n4 = 0; n4 < 4; n4++) acc1[mt][n4] = zero4;
            #pragma unroll
            for (int n4 = 0; n4 < 4; n4++) {
                int nt = h*4 + n4;
                bh8 bf0 = ((const bh8*)w2p)[(nt*4+0)*64 + l];
                bh8 bf1 = ((const bh8*)w2p)[(nt*4+1)*64 + l];
                bh8 bf2 = ((const bh8*)w2p)[(nt*4+2)*64 + l];
                bh8 bf3 = ((const bh8*)w2p)[(nt*4+3)*64 + l];
                #pragma unroll
                for (int mt = 0; mt < 2; mt++) {
                    acc1[mt][n4] = __builtin_amdgcn_mfma_f32_16x16x32_bf16(afrag[mt][0], bf0, acc1[mt][n4], 0,0,0);
                    acc1[mt][n4] = __builtin_amdgcn_mfma_f32_16x16x32_bf16(afrag[mt][1], bf1, acc1[mt][n4], 0,0,0);
                    acc1[mt][n4] = __builtin_amdgcn_mfma_f32_16x16x32_bf16(afrag[mt][2], bf2, acc1[mt][n4], 0,0,0);
                    acc1[mt][n4] = __builtin_amdgcn_mfma_f32_16x16x32_bf16(afrag[mt][3], bf3, acc1[mt][n4], 0,0,0);
                }
            }
            // epilogue for this half -> H2 slab (swizzled)
            #pragma unroll
            for (int mt = 0; mt < 2; mt++)
            #pragma unroll
            for (int n4 = 0; n4 < 4; n4++) {
                int col = (h*4 + n4)*16 + lr;
                float bb2 = b2L[col];
                #pragma unroll
                for (int reg = 0; reg < 4; reg++) {
                    int sl = mt*16 + lq*4 + reg;
                    float v = fmaxf(acc1[mt][n4][reg] + bb2, 0.f);
                    int g2 = (col >> 3) ^ (sl & 7);
                    slab[sl*128 + (g2<<3) + (col & 7)] = f2bf(v);
                }
            }
            __builtin_amdgcn_sched_barrier(0);   // keep halves' register pressure separate
        }
        __syncthreads();

        // ---- extract A-frags of H2 into registers (frees the slab for CIN) ----
        bh8 afr2[2][4];
        #pragma unroll
        for (int mt = 0; mt < 2; mt++)
        #pragma unroll
        for (int k0 = 0; k0 < 4; k0++) {
            int sl = mt*16 + lr;
            int g2 = (k0*4 + lq) ^ (sl & 7);
            afr2[mt][k0] = *(const bh8*)&slab[sl*128 + (g2<<3)];
        }
        __syncthreads();   // lgkm drain: all slab reads complete before CIN overwrites

        // ---- GEMM2: [feat(32) | sigma | pad] = H2 . [Wf|Wd|0] ----
        f32x4 acc2[2][3];
        #pragma unroll
        for (int mt = 0; mt < 2; mt++)
        #pragma unroll
        for (int nt = 0; nt < 3; nt++) acc2[mt][nt] = zero4;
        #pragma unroll
        for (int nt = 0; nt < 3; nt++) {
            bh8 bf0 = ((const bh8*)wfdp)[(nt*4+0)*64 + l];
            bh8 bf1 = ((const bh8*)wfdp)[(nt*4+1)*64 + l];
            bh8 bf2 = ((const bh8*)wfdp)[(nt*4+2)*64 + l];
            bh8 bf3 = ((const bh8*)wfdp)[(nt*4+3)*64 + l];
            #pragma unroll
            for (int mt = 0; mt < 2; mt++) {
                acc2[mt][nt] = __builtin_amdgcn_mfma_f32_16x16x32_bf16(afr2[mt][0], bf0, acc2[mt][nt], 0,0,0);
                acc2[mt][nt] = __builtin_amdgcn_mfma_f32_16x16x32_bf16(afr2[mt][1], bf1, acc2[mt][nt], 0,0,0);
                acc2[mt][nt] = __builtin_amdgcn_mfma_f32_16x16x32_bf16(afr2[mt][2], bf2, acc2[mt][nt], 0,0,0);
                acc2[mt][nt] = __builtin_amdgcn_mfma_f32_16x16x32_bf16(afr2[mt][3], bf3, acc2[mt][nt], 0,0,0);
            }
        }
        // sigma (col 32 = ntile2,col0): softplus * wv -> partial store
        if (lr == 0) {
            #pragma unroll
            for (int mt = 0; mt < 2; mt++)
            #pragma unroll
            for (int reg = 0; reg < 4; reg++) {
                int sg = sbase + mt*16 + lq*4 + reg;
                float x = acc2[mt][2][reg] + bdL;
                float sgm = log1pf(expf(-fabsf(x))) + fmaxf(x, 0.f);
                tdg[sg] = sgm * wvL[sg];
            }
        }
        // feat -> CIN slab cols 0..31 (swizzled, row stride 64)
        #pragma unroll
        for (int mt = 0; mt < 2; mt++)
        #pragma unroll
        for (int nt = 0; nt < 2; nt++) {
            int f = nt*16 + lr;
            #pragma unroll
            for (int reg = 0; reg < 4; reg++) {
                int sl = mt*16 + lq*4 + reg;
                int g2 = (f >> 3) ^ (sl & 7);
                slab[sl*64 + (g2<<3) + (f & 7)] = f2bf(acc2[mt][nt][reg]);
            }
        }
        // CIN extras cols 32..63 = [d(3), emb(16), exp(1), 0-pad]
        {
            int sl = l & 31, cg = l >> 5;
            #pragma unroll
            for (int j = 0; j < 16; j++) {
                int c = 32 + cg*16 + j;
                float v;
                if (c < 35)       v = (c==32 ? dx : (c==33 ? dy : dz));
                else if (c < 51)  v = embL[c-35];
                else if (c == 51) v = expv;
                else              v = 0.f;
                int g2 = (c >> 3) ^ (sl & 7);
                slab[sl*64 + (g2<<3) + (c & 7)] = f2bf(v);
            }
        }
        __syncthreads();

        // ---- GEMM3: HC[32][64] = relu(CIN . Wc1 + bc1) ----
        bh8 afr3[2][2];
        #pragma unroll
        for (int mt = 0; mt < 2; mt++)
        #pragma unroll
        for (int k0 = 0; k0 < 2; k0++) {
            int sl = mt*16 + lr;
            int g2 = (k0*4 + lq) ^ (sl & 7);
            afr3[mt][k0] = *(const bh8*)&slab[sl*64 + (g2<<3)];
        }
        f32x4 acc3[2][4];
        #pragma unroll
        for (int mt = 0; mt < 2; mt++)
        #pragma unroll
        for (int nt = 0; nt < 4; nt++) acc3[mt][nt] = zero4;
        #pragma unroll
        for (int nt = 0; nt < 4; nt++) {
            bh8 bf0 = ((const bh8*)wc1p)[(nt*2+0)*64 + l];
            bh8 bf1 = ((const bh8*)wc1p)[(nt*2+1)*64 + l];
            #pragma unroll
            for (int mt = 0; mt < 2; mt++) {
                acc3[mt][nt] = __builtin_amdgcn_mfma_f32_16x16x32_bf16(afr3[mt][0], bf0, acc3[mt][nt], 0,0,0);
                acc3[mt][nt] = __builtin_amdgcn_mfma_f32_16x16x32_bf16(afr3[mt][1], bf1, acc3[mt][nt], 0,0,0);
            }
        }
        // color: hc=relu(+bc1); dot wc2; 16-lane reduce; sigmoid * wv -> partial store
        #pragma unroll
        for (int mt = 0; mt < 2; mt++)
        #pragma unroll
        for (int reg = 0; reg < 4; reg++) {
            float p0 = 0.f, p1 = 0.f, p2 = 0.f;
            #pragma unroll
            for (int nt = 0; nt < 4; nt++) {
                int e = nt*16 + lr;
                float hc = fmaxf(acc3[mt][nt][reg] + bc1L[e], 0.f);
                p0 = fmaf(hc, wc2L[e*3+0], p0);
                p1 = fmaf(hc, wc2L[e*3+1], p1);
                p2 = fmaf(hc, wc2L[e*3+2], p2);
            }
            #pragma unroll
            for (int m = 1; m < 16; m <<= 1) {
                p0 += __shfl_xor(p0, m);
                p1 += __shfl_xor(p1, m);
                p2 += __shfl_xor(p2, m);
            }
            if (lr == 0) {
                int sg = sbase + mt*16 + lq*4 + reg;
                float wvv = wvL[sg];
                c0g[sg] = wvv / (1.f + expf(-(p0 + bc2L[0])));
                c1g[sg] = wvv / (1.f + expf(-(p1 + bc2L[1])));
                c2g[sg] = wvv / (1.f + expf(-(p2 + bc2L[2])));
            }
        }
        __syncthreads();   // protect slab before next pass overwrites
    }
}

// ---------------- composite: sum k-partials, sequential scan ----------------
__global__ __launch_bounds__(256) void comp_kernel(
    const float* __restrict__ ro, const float* __restrict__ rd,
    const float* __restrict__ nearp, const float* __restrict__ farp,
    const int* __restrict__ selw, const float* __restrict__ cselw,
    const float* __restrict__ tdp, const float* __restrict__ c0p,
    const float* __restrict__ c1p, const float* __restrict__ c2p,
    float* __restrict__ out)
{
    const int r = blockIdx.x, t = threadIdx.x;
    __shared__ int selLds[KSEL];
    __shared__ float cselLds[KSEL*3];
    __shared__ float aLds[SNUM], cn0[SNUM], cn1[SNUM], cn2[SNUM];
    if (t < KSEL) selLds[t] = selw[r*KSEL + t];
    if (t < KSEL*3) cselLds[t] = cselw[r*KSEL*3 + t];
    __syncthreads();
    const float ox = ro[r*3], oy = ro[r*3+1], oz = ro[r*3+2];
    const float dx = rd[r*3], dy = rd[r*3+1], dz = rd[r*3+2];
    const float nearr = nearp[r];
    {
        const int s = t;
        float ts = nearr + STEPF*(float)s;
        float px = ox + ts*dx, py = oy + ts*dy, pz = oz + ts*dz;
        float invv[KSEL]; float wsum = 0.f;
        #pragma unroll
        for (int k2 = 0; k2 < KSEL; k2++) {
            float inv = 0.f;
            if (selLds[k2] >= 0) {
                float ex = px - cselLds[k2*3], ey = py - cselLds[k2*3+1], ez = pz - cselLds[k2*3+2];
                inv = 1.f / (sqrtf(ex*ex + ey*ey + ez*ez) + 1e-6f);
            }
            invv[k2] = inv; wsum += inv;
        }
        float tw = 0.f;
        #pragma unroll
        for (int k2 = 0; k2 < KSEL; k2++) {
            float w = (wsum > 0.f) ? invv[k2] / fmaxf(wsum, 1e-12f) : 0.f;
            if (w >= VIS_T && selLds[k2] >= 0) tw += w;
        }
        float td = 0.f, c0 = 0.f, c1 = 0.f, c2 = 0.f;
        #pragma unroll
        for (int k2 = 0; k2 < KSEL; k2++) {
            size_t gg = (size_t)(r*KSEL + k2)*SNUM + s;
            td += tdp[gg]; c0 += c0p[gg]; c1 += c1p[gg]; c2 += c2p[gg];
        }
        float a = fminf(fmaxf(1.f - expf(-td*STEPF), 0.f), 1.f);
        if (tw > 0.f) {
            float dv = fmaxf(tw, 1e-12f);
            c0 /= dv; c1 /= dv; c2 /= dv;
        }
        aLds[s] = a; cn0[s] = c0; cn1[s] = c1; cn2[s] = c2;
    }
    __syncthreads();
    if (t == 0) {
        const float farr = farp[r];
        float T = 1.f, acc = 0.f, rgb0=0.f, rgb1=0.f, rgb2=0.f, dep=0.f;
        for (int s = 0; s < SNUM; s++) {
            float ts = nearr + STEPF*(float)s;
            bool alive = (ts < farr) && (T > T_EPS) && (acc <= TERM_T);
            float a = aLds[s];
            float wgt = alive ? T*a : 0.f;
            rgb0 += wgt*cn0[s]; rgb1 += wgt*cn1[s]; rgb2 += wgt*cn2[s];
            acc += wgt;
            dep += wgt*ts;
            T *= alive ? (1.f - a) : 1.f;
        }
        float depth = dep / fmaxf(acc, 1e-6f);
        out[r*3+0] = rgb0;
        out[r*3+1] = rgb1;
        out[r*3+2] = rgb2;
        out[RNUM*3 + r]        = depth;
        out[RNUM*3 + RNUM + r] = acc;
    }
}

extern "C" void kernel_launch(void* const* d_in, const int* in_sizes, int n_in,
                              void* d_out, int out_size, void* d_ws, size_t ws_size,
                              hipStream_t stream) {
    const float* ro    = (const float*)d_in[0];
    const float* rd    = (const float*)d_in[1];
    const float* bc    = (const float*)d_in[2];
    const float* br    = (const float*)d_in[3];
    const int*   aidp  = (const int*)d_in[4];
    const float* expo  = (const float*)d_in[5];
    const float* nearp = (const float*)d_in[6];
    const float* farp  = (const float*)d_in[7];
    const float* W1    = (const float*)d_in[8];
    const float* b1    = (const float*)d_in[9];
    const float* W2    = (const float*)d_in[10];
    const float* b2    = (const float*)d_in[11];
    const float* Wd    = (const float*)d_in[12];
    const float* bd    = (const float*)d_in[13];
    const float* Wf    = (const float*)d_in[14];
    const float* Wc1   = (const float*)d_in[15];
    const float* bc1   = (const float*)d_in[16];
    const float* Wc2   = (const float*)d_in[17];
    const float* bc2   = (const float*)d_in[18];
    const float* appe  = (const float*)d_in[19];
    float* outp = (float*)d_out;

    // workspace layout (float units from base)
    float* wsf = (float*)d_ws;
    unsigned short* wsu = (unsigned short*)d_ws;          // 64*26624 ush = 3,407,872 B
    int*   selw  = (int*)  (wsf + 851968);                // 2048 ints
    float* cselw =         wsf + 854016;                  // 6144 f32
    float* tdp   =         wsf + 860160;                  // 2048*256
    float* c0p   =         tdp + 2048*SNUM;
    float* c1p   =         c0p + 2048*SNUM;
    float* c2p   =         c1p + 2048*SNUM;               // end ~11.83 MB

    pre_kernel<<<4*NB + RNUM, 256, 0, stream>>>(ro, rd, bc, br, W2, Wf, Wd, Wc1,
                                                wsu, selw, cselw);
    mlp_kernel<<<RNUM*KSEL, 256, 0, stream>>>(ro, rd, nearp, expo, aidp,
                                              W1, b1, b2, bd, bc1, Wc2, bc2, appe,
                                              wsu, selw, cselw, tdp, c0p, c1p, c2p);
    comp_kernel<<<RNUM, 256, 0, stream>>>(ro, rd, nearp, farp, selw, cselw,
                                          tdp, c0p, c1p, c2p, outp);
}